// Round 4
// baseline (1101.039 us; speedup 1.0000x reference)
//
#include <hip/hip_runtime.h>
#include <hip/hip_bf16.h>

// ---------------------------------------------------------------------------
// GNN encoder: SAGEConv -> BN -> 2x (GINConv -> BN), concat outputs + add-pool
// N=100000, E=1600000, F=D=128, L=3, G=500
// Round 3: bf16 gather tables + MFMA GEMMs with hi/lo-split weights
// (W = W_hi + W_lo, 2 MFMAs per fragment) to kill the correlated W-rounding
// error that failed round 2. W fragments read from L2 (no LDS, no barrier).
// ---------------------------------------------------------------------------

#define BN_EPS 1e-5f

typedef short s8v __attribute__((ext_vector_type(8)));
typedef float f4v __attribute__((ext_vector_type(4)));

__device__ __forceinline__ float bflo(unsigned u) { return __uint_as_float(u << 16); }
__device__ __forceinline__ float bfhi(unsigned u) { return __uint_as_float(u & 0xffff0000u); }
__device__ __forceinline__ unsigned short f2bf(float f) {
    unsigned u = __float_as_uint(f);
    unsigned r = (u + 0x7fffu + ((u >> 16) & 1u)) >> 16;  // RTNE
    return (unsigned short)r;
}
__device__ __forceinline__ unsigned pk2(float a, float b) {
    return (unsigned)f2bf(a) | ((unsigned)f2bf(b) << 16);
}
__device__ __forceinline__ void unpack8(uint4 u, float* v) {
    v[0] = bflo(u.x); v[1] = bfhi(u.x);
    v[2] = bflo(u.y); v[3] = bfhi(u.y);
    v[4] = bflo(u.z); v[5] = bfhi(u.z);
    v[6] = bflo(u.w); v[7] = bfhi(u.w);
}

// ---------------- CSR build ----------------

__global__ void k_count(const int* __restrict__ dst, int E, int* __restrict__ cnt) {
    int e = blockIdx.x * 256 + threadIdx.x;
    if (e < E) atomicAdd(&cnt[dst[e]], 1);
}

__global__ void k_scan_a(const int* __restrict__ deg, int N, int* __restrict__ bsum) {
    __shared__ int sm[256];
    int base = blockIdx.x * 1024;
    int s = 0;
#pragma unroll
    for (int t = 0; t < 4; t++) {
        int i = base + threadIdx.x + t * 256;
        if (i < N) s += deg[i];
    }
    sm[threadIdx.x] = s;
    __syncthreads();
    for (int off = 128; off > 0; off >>= 1) {
        if (threadIdx.x < off) sm[threadIdx.x] += sm[threadIdx.x + off];
        __syncthreads();
    }
    if (threadIdx.x == 0) bsum[blockIdx.x] = sm[0];
}

__global__ void k_scan_b(const int* __restrict__ bsum, int nb, int* __restrict__ bbase) {
    if (threadIdx.x == 0) {
        int run = 0;
        for (int i = 0; i < nb; i++) { bbase[i] = run; run += bsum[i]; }
    }
}

__global__ void k_scan_c(int* __restrict__ deg_cursor, int N,
                         const int* __restrict__ bbase, int* __restrict__ rp, int E) {
    __shared__ int sm[256];
    int base = blockIdx.x * 1024 + threadIdx.x * 4;
    int v[4];
    int s = 0;
#pragma unroll
    for (int t = 0; t < 4; t++) {
        int i = base + t;
        v[t] = (i < N) ? deg_cursor[i] : 0;
        s += v[t];
    }
    sm[threadIdx.x] = s;
    __syncthreads();
    for (int off = 1; off < 256; off <<= 1) {
        int y = (threadIdx.x >= off) ? sm[threadIdx.x - off] : 0;
        __syncthreads();
        sm[threadIdx.x] += y;
        __syncthreads();
    }
    int excl = sm[threadIdx.x] - s;
    int b = bbase[blockIdx.x] + excl;
#pragma unroll
    for (int t = 0; t < 4; t++) {
        int i = base + t;
        if (i < N) { rp[i] = b; deg_cursor[i] = b; b += v[t]; }
    }
    if (blockIdx.x == 0 && threadIdx.x == 0) rp[N] = E;
}

__global__ void k_fill(const int* __restrict__ src, const int* __restrict__ dst, int E,
                       int* __restrict__ cursor, int* __restrict__ csr) {
    int e = blockIdx.x * 256 + threadIdx.x;
    if (e < E) {
        int pos = atomicAdd(&cursor[dst[e]], 1);
        csr[pos] = src[e];
    }
}

// ---------------- conversions / weight packing ----------------

// f32 -> bf16, 8 elems/thread
__global__ void k_cvt_bf16(const float* __restrict__ in, uint4* __restrict__ out, int n8) {
    int i = blockIdx.x * 256 + threadIdx.x;
    if (i >= n8) return;
    const float4* p = reinterpret_cast<const float4*>(in) + (size_t)i * 2;
    float4 a = p[0], b = p[1];
    uint4 o;
    o.x = pk2(a.x, a.y); o.y = pk2(a.z, a.w);
    o.z = pk2(b.x, b.y); o.w = pk2(b.z, b.w);
    out[i] = o;
}

// pack one 128x128 f32 W into MFMA A-operand (W^T) fragment layout, split into
// bf16 hi plane (+0) and bf16 lo-residual plane (+16384):
// plane[((k>>3)*128 + d)*8 + (k&7)]
__global__ void k_pack_w(const float* __restrict__ W, unsigned short* __restrict__ out) {
    int idx = blockIdx.x * 256 + threadIdx.x;  // 16384
    int k = idx >> 7, d = idx & 127;
    float w = W[idx];
    unsigned short h = f2bf(w);
    float hf = __uint_as_float((unsigned)h << 16);
    unsigned short l = f2bf(w - hf);
    int o = (((k >> 3) * 128) + d) * 8 + (k & 7);
    out[o] = h;
    out[16384 + o] = l;
}

// ---------------- aggregation (bf16 src rows, 16 lanes x 16B per node) -----

template <bool SELF, bool MEAN>
__global__ void k_aggr(const int* __restrict__ rp, const int* __restrict__ csr,
                       const uint4* __restrict__ src, uint4* __restrict__ out, int N) {
    int node = blockIdx.x * 16 + (threadIdx.x >> 4);
    if (node >= N) return;
    int c = threadIdx.x & 15;
    float acc[8];
    if (SELF) {
        unpack8(src[(size_t)node * 16 + c], acc);
    } else {
#pragma unroll
        for (int k = 0; k < 8; k++) acc[k] = 0.f;
    }
    int lo = rp[node], hi = rp[node + 1];
    for (int j = lo; j < hi; j++) {
        int sn = csr[j];
        float v[8];
        unpack8(src[(size_t)sn * 16 + c], v);
#pragma unroll
        for (int k = 0; k < 8; k++) acc[k] += v[k];
    }
    if (MEAN) {
        float inv = 1.0f / fmaxf((float)(hi - lo), 1.0f);
#pragma unroll
        for (int k = 0; k < 8; k++) acc[k] *= inv;
    }
    uint4 o;
    o.x = pk2(acc[0], acc[1]); o.y = pk2(acc[2], acc[3]);
    o.z = pk2(acc[4], acc[5]); o.w = pk2(acc[6], acc[7]);
    out[(size_t)node * 16 + c] = o;
}

// ---------------- MFMA GEMM ----------------
// C = relu( sum_t A_t @ (Whi_t + Wlo_t) + bias ), A_t: [N x 128] bf16 rows.
// Swapped operands: mfma(A_op = W^T frag, B_op = node frag) -> C^T frags,
// lane holds node = l16, d = df*16 + lg*4 + reg (4 contiguous d per lane).
// W fragments streamed from global (L2-resident, 64KB/term). No LDS.
// Block: 256 thr = 4 waves; wave = 32 nodes; block = 128 nodes. K=128/term.

template <int TERMS, bool F32OUT>
__global__ __launch_bounds__(256) void k_gemm_mfma(
    const uint4* __restrict__ A1, const uint4* __restrict__ A2,
    const uint4* __restrict__ Wfrag,  // TERMS * 2 * 2048 uint4: [term][hi,lo]
    const float* __restrict__ bias,
    float* __restrict__ outF,                 // if F32OUT: stride 384
    unsigned short* __restrict__ outB,        // else: compact bf16 [N][128]
    int N) {
    const int tid = threadIdx.x;
    const int lane = tid & 63, wid = tid >> 6;
    const int nbase = blockIdx.x * 128 + wid * 32;
    const int l16 = lane & 15, lg = lane >> 4;

    f4v acc[2][8];
#pragma unroll
    for (int nf = 0; nf < 2; nf++)
#pragma unroll
        for (int df = 0; df < 8; df++) {
            acc[nf][df][0] = 0.f; acc[nf][df][1] = 0.f;
            acc[nf][df][2] = 0.f; acc[nf][df][3] = 0.f;
        }

#pragma unroll
    for (int t = 0; t < TERMS; t++) {
        const uint4* A = t ? A2 : A1;
        const uint4* Whi = Wfrag + (size_t)t * 4096;
        const uint4* Wlo = Whi + 2048;
        // node (B-operand) fragments: lane reads 16B of its node's row
        uint4 bvec[2][4];
#pragma unroll
        for (int nf = 0; nf < 2; nf++) {
            const uint4* row = A + (size_t)(nbase + nf * 16 + l16) * 16;
#pragma unroll
            for (int ks = 0; ks < 4; ks++) bvec[nf][ks] = row[ks * 4 + lg];
        }
#pragma unroll
        for (int ks = 0; ks < 4; ks++) {
            s8v b0 = __builtin_bit_cast(s8v, bvec[0][ks]);
            s8v b1 = __builtin_bit_cast(s8v, bvec[1][ks]);
#pragma unroll
            for (int df = 0; df < 8; df++) {
                int wi = (ks * 4 + lg) * 128 + df * 16 + l16;
                s8v ah = __builtin_bit_cast(s8v, Whi[wi]);
                s8v al = __builtin_bit_cast(s8v, Wlo[wi]);
                acc[0][df] = __builtin_amdgcn_mfma_f32_16x16x32_bf16(ah, b0, acc[0][df], 0, 0, 0);
                acc[1][df] = __builtin_amdgcn_mfma_f32_16x16x32_bf16(ah, b1, acc[1][df], 0, 0, 0);
                acc[0][df] = __builtin_amdgcn_mfma_f32_16x16x32_bf16(al, b0, acc[0][df], 0, 0, 0);
                acc[1][df] = __builtin_amdgcn_mfma_f32_16x16x32_bf16(al, b1, acc[1][df], 0, 0, 0);
            }
        }
    }

#pragma unroll
    for (int nf = 0; nf < 2; nf++) {
        int n = nbase + nf * 16 + l16;
        if (n < N) {
#pragma unroll
            for (int df = 0; df < 8; df++) {
                int d0 = df * 16 + lg * 4;
                const float4 bb = *reinterpret_cast<const float4*>(bias + d0);
                float4 o;
                o.x = fmaxf(acc[nf][df][0] + bb.x, 0.f);
                o.y = fmaxf(acc[nf][df][1] + bb.y, 0.f);
                o.z = fmaxf(acc[nf][df][2] + bb.z, 0.f);
                o.w = fmaxf(acc[nf][df][3] + bb.w, 0.f);
                if (F32OUT) {
                    *reinterpret_cast<float4*>(outF + (size_t)n * 384 + d0) = o;
                } else {
                    uint2 p;
                    p.x = pk2(o.x, o.y);
                    p.y = pk2(o.z, o.w);
                    *reinterpret_cast<uint2*>(outB + (size_t)n * 128 + d0) = p;
                }
            }
        }
    }
}

// ---------------- BatchNorm ----------------

template <bool BF16>
__global__ __launch_bounds__(256) void k_stats2(const void* __restrict__ in, int ldin, int N,
                                                float* __restrict__ gsum, float* __restrict__ gsq) {
    __shared__ float ss[16][16][8];
    __shared__ float sq[16][16][8];
    int c = threadIdx.x & 15, r = threadIdx.x >> 4;
    float s[8], q[8];
#pragma unroll
    for (int k = 0; k < 8; k++) { s[k] = 0.f; q[k] = 0.f; }
    for (int n = blockIdx.x * 16 + r; n < N; n += gridDim.x * 16) {
        float v[8];
        if (BF16) {
            unpack8(reinterpret_cast<const uint4*>(in)[(size_t)n * 16 + c], v);
        } else {
            const float* p = (const float*)in + (size_t)n * ldin + c * 8;
            float4 x0 = *reinterpret_cast<const float4*>(p);
            float4 x1 = *reinterpret_cast<const float4*>(p + 4);
            v[0] = x0.x; v[1] = x0.y; v[2] = x0.z; v[3] = x0.w;
            v[4] = x1.x; v[5] = x1.y; v[6] = x1.z; v[7] = x1.w;
        }
#pragma unroll
        for (int k = 0; k < 8; k++) { s[k] += v[k]; q[k] = fmaf(v[k], v[k], q[k]); }
    }
#pragma unroll
    for (int k = 0; k < 8; k++) { ss[r][c][k] = s[k]; sq[r][c][k] = q[k]; }
    __syncthreads();
    for (int off = 8; off > 0; off >>= 1) {
        if (r < off) {
#pragma unroll
            for (int k = 0; k < 8; k++) {
                ss[r][c][k] += ss[r + off][c][k];
                sq[r][c][k] += sq[r + off][c][k];
            }
        }
        __syncthreads();
    }
    if (r == 0) {
#pragma unroll
        for (int k = 0; k < 8; k++) {
            unsafeAtomicAdd(&gsum[c * 8 + k], ss[0][c][k]);
            unsafeAtomicAdd(&gsq[c * 8 + k], sq[0][c][k]);
        }
    }
}

__global__ void k_bnfin(const float* __restrict__ gsum, const float* __restrict__ gsq,
                        const float* __restrict__ gamma, const float* __restrict__ beta,
                        int N, float* __restrict__ a, float* __restrict__ c) {
    int d = threadIdx.x;  // 128
    float invN = 1.0f / (float)N;
    float mu = gsum[d] * invN;
    float var = gsq[d] * invN - mu * mu;
    float rs = rsqrtf(var + BN_EPS);
    float aa = gamma[d] * rs;
    a[d] = aa;
    c[d] = beta[d] - mu * aa;
}

// normalize: outF[n*384+f] = v*a[f]+c[f] ; optional compact bf16 copy
template <bool BF16IN>
__global__ void k_norm2(const void* __restrict__ in, int ldin,
                        const float* __restrict__ sa, const float* __restrict__ sc,
                        float* __restrict__ outF, uint4* __restrict__ outB, int N) {
    int idx = blockIdx.x * 256 + threadIdx.x;
    if (idx >= N * 16) return;
    int n = idx >> 4, cc = idx & 15;
    float v[8];
    if (BF16IN) {
        unpack8(reinterpret_cast<const uint4*>(in)[(size_t)n * 16 + cc], v);
    } else {
        const float* p = (const float*)in + (size_t)n * ldin + cc * 8;
        float4 x0 = *reinterpret_cast<const float4*>(p);
        float4 x1 = *reinterpret_cast<const float4*>(p + 4);
        v[0] = x0.x; v[1] = x0.y; v[2] = x0.z; v[3] = x0.w;
        v[4] = x1.x; v[5] = x1.y; v[6] = x1.z; v[7] = x1.w;
    }
    const float4 a0 = *reinterpret_cast<const float4*>(sa + cc * 8);
    const float4 a1 = *reinterpret_cast<const float4*>(sa + cc * 8 + 4);
    const float4 c0 = *reinterpret_cast<const float4*>(sc + cc * 8);
    const float4 c1 = *reinterpret_cast<const float4*>(sc + cc * 8 + 4);
    float y[8];
    y[0] = fmaf(v[0], a0.x, c0.x); y[1] = fmaf(v[1], a0.y, c0.y);
    y[2] = fmaf(v[2], a0.z, c0.z); y[3] = fmaf(v[3], a0.w, c0.w);
    y[4] = fmaf(v[4], a1.x, c1.x); y[5] = fmaf(v[5], a1.y, c1.y);
    y[6] = fmaf(v[6], a1.z, c1.z); y[7] = fmaf(v[7], a1.w, c1.w);
    float* po = outF + (size_t)n * 384 + cc * 8;
    *reinterpret_cast<float4*>(po) = make_float4(y[0], y[1], y[2], y[3]);
    *reinterpret_cast<float4*>(po + 4) = make_float4(y[4], y[5], y[6], y[7]);
    if (outB) {
        uint4 o;
        o.x = pk2(y[0], y[1]); o.y = pk2(y[2], y[3]);
        o.z = pk2(y[4], y[5]); o.w = pk2(y[6], y[7]);
        outB[(size_t)n * 16 + cc] = o;
    }
}

// ---------------- pooling ----------------

__device__ __forceinline__ int lbound(const int* __restrict__ b, int n, int v) {
    int lo = 0, hi = n;
    while (lo < hi) {
        int m = (lo + hi) >> 1;
        if (b[m] < v) lo = m + 1; else hi = m;
    }
    return lo;
}

__global__ void k_pool(const float* __restrict__ nf, const int* __restrict__ batch,
                       int N, float* __restrict__ out) {
    int g = blockIdx.x;
    int d = threadIdx.x;  // 384
    int lo = lbound(batch, N, g);
    int hi = lbound(batch, N, g + 1);
    float s = 0.f;
    for (int n = lo; n < hi; n++) s += nf[(size_t)n * 384 + d];
    out[(size_t)g * 384 + d] = s;
}

// ---------------- launch ----------------

extern "C" void kernel_launch(void* const* d_in, const int* in_sizes, int n_in,
                              void* d_out, int out_size, void* d_ws, size_t ws_size,
                              hipStream_t stream) {
    const float* x   = (const float*)d_in[0];
    const int*   ei  = (const int*)d_in[1];
    const int*   bat = (const int*)d_in[2];
    const float* sWl = (const float*)d_in[3];
    const float* sbl = (const float*)d_in[4];
    const float* sWr = (const float*)d_in[5];
    const float* gW1 = (const float*)d_in[6];
    const float* gb1 = (const float*)d_in[7];
    const float* gW2 = (const float*)d_in[8];
    const float* gb2 = (const float*)d_in[9];
    const float* bng = (const float*)d_in[10];
    const float* bnb = (const float*)d_in[11];

    const int N = in_sizes[0] / 128;
    const int E = in_sizes[1] / 2;
    const int G = out_size / 384 - N;
    const int* srcp = ei;
    const int* dstp = ei + E;

    char* w = (char*)d_ws;
    auto alloc = [&](size_t bytes) -> void* {
        void* p = (void*)w;
        w += (bytes + 255) & ~(size_t)255;
        return p;
    };
    const size_t Npad = (size_t)(N + 128);
    int*   rp     = (int*)alloc(((size_t)N + 1) * 4);
    int*   cursor = (int*)alloc((size_t)N * 4);
    int*   csr    = (int*)alloc((size_t)E * 4);
    int*   bsum   = (int*)alloc(4096);
    int*   bbase  = (int*)alloc(4096);
    float* gsum   = (float*)alloc(512);
    float* gsq    = (float*)alloc(512);     // contiguous with gsum
    float* abuf   = (float*)alloc(512);
    float* cbuf   = (float*)alloc(512);
    // 6 weights x (hi plane + lo plane) x 16384 bf16
    unsigned short* Wp = (unsigned short*)alloc((size_t)6 * 2 * 16384 * 2);
    unsigned short* ab = (unsigned short*)alloc(Npad * 256);  // bf16 [N][128] (+pad)
    unsigned short* tb = (unsigned short*)alloc(Npad * 256);  // bf16 [N][128] (+pad)

    float* pooled = (float*)d_out;                 // [G][384]
    float* nf     = pooled + (size_t)G * 384;      // [N][384]

    const int nb     = (N + 1023) / 1024;
    const int egrid  = (E + 255) / 256;
    const int agrid  = (N + 15) / 16;
    const int ggrid  = (N + 127) / 128;
    const int vgrid  = (N * 16 + 255) / 256;

    // ---- CSR build ----
    hipMemsetAsync(cursor, 0, (size_t)N * 4, stream);
    k_count<<<egrid, 256, 0, stream>>>(dstp, E, cursor);
    k_scan_a<<<nb, 256, 0, stream>>>(cursor, N, bsum);
    k_scan_b<<<1, 64, 0, stream>>>(bsum, nb, bbase);
    k_scan_c<<<nb, 256, 0, stream>>>(cursor, N, bbase, rp, E);
    k_fill<<<egrid, 256, 0, stream>>>(srcp, dstp, E, cursor, csr);

    // ---- prep: x -> bf16 (in tb), pack weights (hi+lo planes) ----
    k_cvt_bf16<<<vgrid, 256, 0, stream>>>(x, (uint4*)tb, N * 16);
    k_pack_w<<<64, 256, 0, stream>>>(sWl,         Wp + 0 * 32768);
    k_pack_w<<<64, 256, 0, stream>>>(sWr,         Wp + 1 * 32768);
    k_pack_w<<<64, 256, 0, stream>>>(gW1,         Wp + 2 * 32768);
    k_pack_w<<<64, 256, 0, stream>>>(gW2,         Wp + 3 * 32768);
    k_pack_w<<<64, 256, 0, stream>>>(gW1 + 16384, Wp + 4 * 32768);
    k_pack_w<<<64, 256, 0, stream>>>(gW2 + 16384, Wp + 5 * 32768);

    // ---- Layer 0: SAGE ----
    k_aggr<false, true><<<agrid, 256, 0, stream>>>(rp, csr, (const uint4*)tb, (uint4*)ab, N);
    // h0(pre-BN, relu'd) = relu(aggr@Wl + bl + x@Wr) -> nf slice 0 (f32, stride 384)
    k_gemm_mfma<2, true><<<ggrid, 256, 0, stream>>>(
        (const uint4*)ab, (const uint4*)tb, (const uint4*)Wp, sbl, nf, nullptr, N);
    hipMemsetAsync(gsum, 0, 1024, stream);
    k_stats2<false><<<512, 256, 0, stream>>>(nf, 384, N, gsum, gsq);
    k_bnfin<<<1, 128, 0, stream>>>(gsum, gsq, bng, bnb, N, abuf, cbuf);
    // normalize in place + compact bf16 h0 -> tb
    k_norm2<false><<<vgrid, 256, 0, stream>>>(nf, 384, abuf, cbuf, nf, (uint4*)tb, N);

    // ---- Layers 1,2: GIN ----
    for (int l = 1; l < 3; l++) {
        const uint4* W1p = (const uint4*)(Wp + (size_t)(2 + (l - 1) * 2) * 32768);
        const uint4* W2p = (const uint4*)(Wp + (size_t)(3 + (l - 1) * 2) * 32768);
        const float* b1 = gb1 + (size_t)(l - 1) * 128;
        const float* b2 = gb2 + (size_t)(l - 1) * 128;

        // ab = h + sum_nb h  (gather from tb)
        k_aggr<true, false><<<agrid, 256, 0, stream>>>(rp, csr, (const uint4*)tb, (uint4*)ab, N);
        // t = relu(ab@W1 + b1) -> tb
        k_gemm_mfma<1, false><<<ggrid, 256, 0, stream>>>(
            (const uint4*)ab, nullptr, W1p, b1, nullptr, tb, N);
        // u = relu(t@W2 + b2) -> ab
        k_gemm_mfma<1, false><<<ggrid, 256, 0, stream>>>(
            (const uint4*)tb, nullptr, W2p, b2, nullptr, ab, N);
        hipMemsetAsync(gsum, 0, 1024, stream);
        k_stats2<true><<<512, 256, 0, stream>>>(ab, 128, N, gsum, gsq);
        k_bnfin<<<1, 128, 0, stream>>>(gsum, gsq, bng + l * 128, bnb + l * 128, N, abuf, cbuf);
        // normalize -> nf slice l (f32) + compact bf16 h_l -> tb (not needed after layer 2)
        k_norm2<true><<<vgrid, 256, 0, stream>>>(ab, 128, abuf, cbuf, nf + (size_t)l * 128,
                                                 (l < 2) ? (uint4*)tb : nullptr, N);
    }

    // ---- pooling ----
    k_pool<<<G, 384, 0, stream>>>(nf, bat, N, pooled);
}

// Round 5
// 983.267 us; speedup vs baseline: 1.1198x; 1.1198x over previous
//
#include <hip/hip_runtime.h>
#include <hip/hip_bf16.h>

// ---------------------------------------------------------------------------
// GNN encoder: SAGEConv -> BN -> 2x (GINConv -> BN), concat outputs + add-pool
// N=100000, E=1600000, F=D=128, L=3, G=500
// Round 5: binned CSR build (kills k_fill's 17x write amplification +
// k_count's scattered atomics); GIN u-values kept f32 through BN for margin.
// ---------------------------------------------------------------------------

#define BN_EPS 1e-5f
#define EPB 4096   // edges per block in bin pass A

typedef short s8v __attribute__((ext_vector_type(8)));
typedef float f4v __attribute__((ext_vector_type(4)));

__device__ __forceinline__ float bflo(unsigned u) { return __uint_as_float(u << 16); }
__device__ __forceinline__ float bfhi(unsigned u) { return __uint_as_float(u & 0xffff0000u); }
__device__ __forceinline__ unsigned short f2bf(float f) {
    unsigned u = __float_as_uint(f);
    unsigned r = (u + 0x7fffu + ((u >> 16) & 1u)) >> 16;  // RTNE
    return (unsigned short)r;
}
__device__ __forceinline__ unsigned pk2(float a, float b) {
    return (unsigned)f2bf(a) | ((unsigned)f2bf(b) << 16);
}
__device__ __forceinline__ void unpack8(uint4 u, float* v) {
    v[0] = bflo(u.x); v[1] = bfhi(u.x);
    v[2] = bflo(u.y); v[3] = bfhi(u.y);
    v[4] = bflo(u.z); v[5] = bfhi(u.z);
    v[6] = bflo(u.w); v[7] = bfhi(u.w);
}

// ---------------- CSR build (binned, 2-pass) ----------------
// Pass A: bin edges by dst>>8 into bucket buffer (contiguous runs per block
// per bin -> no write amplification). Pass B: per-bucket LDS degree count +
// scan -> rp, LDS-cursor fill -> csr (writes stay in one ~26KB L2 window).

__global__ __launch_bounds__(256) void k_binA(const int* __restrict__ src,
                                              const int* __restrict__ dst, int E, int NB, int CAP,
                                              int* __restrict__ bcnt,
                                              unsigned long long* __restrict__ ebuf) {
    __shared__ int hist[512], base[512], cur[512];
    const int tid = threadIdx.x;
    const int e0 = blockIdx.x * EPB;
    for (int i = tid; i < 512; i += 256) { hist[i] = 0; cur[i] = 0; }
    __syncthreads();
#pragma unroll
    for (int k = 0; k < EPB / 256; k++) {
        int e = e0 + k * 256 + tid;
        if (e < E) atomicAdd(&hist[dst[e] >> 8], 1);
    }
    __syncthreads();
    for (int b = tid; b < NB; b += 256)
        base[b] = hist[b] ? atomicAdd(&bcnt[b], hist[b]) : 0;
    __syncthreads();
#pragma unroll
    for (int k = 0; k < EPB / 256; k++) {
        int e = e0 + k * 256 + tid;
        if (e < E) {
            int d = dst[e];
            int b = d >> 8;
            int lp = atomicAdd(&cur[b], 1);
            int gp = base[b] + lp;
            if (gp < CAP)
                ebuf[(size_t)b * CAP + gp] = ((unsigned long long)d << 32) | (unsigned)src[e];
        }
    }
}

__global__ void k_bscan(const int* __restrict__ bcnt, int NB, int* __restrict__ bbase) {
    __shared__ int sm[256];
    const int tid = threadIdx.x;
    const int c = (NB + 255) / 256;
    int s = 0;
    for (int k = 0; k < c; k++) { int i = tid * c + k; if (i < NB) s += bcnt[i]; }
    sm[tid] = s;
    __syncthreads();
    for (int off = 1; off < 256; off <<= 1) {
        int v = (tid >= off) ? sm[tid - off] : 0;
        __syncthreads();
        sm[tid] += v;
        __syncthreads();
    }
    int run = sm[tid] - s;
    for (int k = 0; k < c; k++) {
        int i = tid * c + k;
        if (i < NB) { bbase[i] = run; run += bcnt[i]; }
    }
}

__global__ __launch_bounds__(256) void k_binB(const unsigned long long* __restrict__ ebuf,
                                              int CAP, const int* __restrict__ bcnt,
                                              const int* __restrict__ bbase,
                                              int N, int E,
                                              int* __restrict__ rp, int* __restrict__ csr) {
    __shared__ int deg[256], sc[256], cur[256];
    const int tid = threadIdx.x;
    const int b = blockIdx.x;
    const int cnt = min(bcnt[b], CAP);
    const int cbase = bbase[b];
    deg[tid] = 0;
    __syncthreads();
    const unsigned long long* eb = ebuf + (size_t)b * CAP;
    for (int i = tid; i < cnt; i += 256) {
        int d = (int)(eb[i] >> 32);
        atomicAdd(&deg[d & 255], 1);
    }
    __syncthreads();
    int myDeg = deg[tid];
    sc[tid] = myDeg;
    __syncthreads();
    for (int off = 1; off < 256; off <<= 1) {
        int v = (tid >= off) ? sc[tid - off] : 0;
        __syncthreads();
        sc[tid] += v;
        __syncthreads();
    }
    int pos = cbase + sc[tid] - myDeg;
    int node = b * 256 + tid;
    if (node < N) rp[node] = pos;
    cur[tid] = pos;
    __syncthreads();
    for (int i = tid; i < cnt; i += 256) {
        unsigned long long e = eb[i];
        int d = (int)(e >> 32);
        int p = atomicAdd(&cur[d & 255], 1);
        csr[p] = (int)(e & 0xffffffffu);
    }
    if (b == 0 && tid == 0) rp[N] = E;
}

// ---------------- conversions / weight packing ----------------

__global__ void k_cvt_bf16(const float* __restrict__ in, uint4* __restrict__ out, int n8) {
    int i = blockIdx.x * 256 + threadIdx.x;
    if (i >= n8) return;
    const float4* p = reinterpret_cast<const float4*>(in) + (size_t)i * 2;
    float4 a = p[0], b = p[1];
    uint4 o;
    o.x = pk2(a.x, a.y); o.y = pk2(a.z, a.w);
    o.z = pk2(b.x, b.y); o.w = pk2(b.z, b.w);
    out[i] = o;
}

// pack one 128x128 f32 W into MFMA A-operand (W^T) fragment layout, split into
// bf16 hi plane (+0) and bf16 lo-residual plane (+16384)
__global__ void k_pack_w(const float* __restrict__ W, unsigned short* __restrict__ out) {
    int idx = blockIdx.x * 256 + threadIdx.x;  // 16384
    int k = idx >> 7, d = idx & 127;
    float w = W[idx];
    unsigned short h = f2bf(w);
    float hf = __uint_as_float((unsigned)h << 16);
    unsigned short l = f2bf(w - hf);
    int o = (((k >> 3) * 128) + d) * 8 + (k & 7);
    out[o] = h;
    out[16384 + o] = l;
}

// ---------------- aggregation (bf16 src rows, 16 lanes x 16B per node) -----

template <bool SELF, bool MEAN>
__global__ void k_aggr(const int* __restrict__ rp, const int* __restrict__ csr,
                       const uint4* __restrict__ src, uint4* __restrict__ out, int N) {
    int node = blockIdx.x * 16 + (threadIdx.x >> 4);
    if (node >= N) return;
    int c = threadIdx.x & 15;
    float acc[8];
    if (SELF) {
        unpack8(src[(size_t)node * 16 + c], acc);
    } else {
#pragma unroll
        for (int k = 0; k < 8; k++) acc[k] = 0.f;
    }
    int lo = rp[node], hi = rp[node + 1];
    for (int j = lo; j < hi; j++) {
        int sn = csr[j];
        float v[8];
        unpack8(src[(size_t)sn * 16 + c], v);
#pragma unroll
        for (int k = 0; k < 8; k++) acc[k] += v[k];
    }
    if (MEAN) {
        float inv = 1.0f / fmaxf((float)(hi - lo), 1.0f);
#pragma unroll
        for (int k = 0; k < 8; k++) acc[k] *= inv;
    }
    uint4 o;
    o.x = pk2(acc[0], acc[1]); o.y = pk2(acc[2], acc[3]);
    o.z = pk2(acc[4], acc[5]); o.w = pk2(acc[6], acc[7]);
    out[(size_t)node * 16 + c] = o;
}

// ---------------- MFMA GEMM ----------------
// C = relu( sum_t A_t @ (Whi_t + Wlo_t) + bias ), A_t: [N x 128] bf16 rows.
// Swapped operands: mfma(A_op = W^T frag, B_op = node frag) -> C^T frags,
// lane holds node = l16, d = df*16 + lg*4 + reg. W streamed from L2, no LDS.

template <int TERMS, bool F32OUT>
__global__ __launch_bounds__(256) void k_gemm_mfma(
    const uint4* __restrict__ A1, const uint4* __restrict__ A2,
    const uint4* __restrict__ Wfrag,  // TERMS * 2 * 2048 uint4: [term][hi,lo]
    const float* __restrict__ bias,
    float* __restrict__ outF,                 // if F32OUT: stride 384
    unsigned short* __restrict__ outB,        // else: compact bf16 [N][128]
    int N) {
    const int tid = threadIdx.x;
    const int lane = tid & 63, wid = tid >> 6;
    const int nbase = blockIdx.x * 128 + wid * 32;
    const int l16 = lane & 15, lg = lane >> 4;

    f4v acc[2][8];
#pragma unroll
    for (int nf = 0; nf < 2; nf++)
#pragma unroll
        for (int df = 0; df < 8; df++) {
            acc[nf][df][0] = 0.f; acc[nf][df][1] = 0.f;
            acc[nf][df][2] = 0.f; acc[nf][df][3] = 0.f;
        }

#pragma unroll
    for (int t = 0; t < TERMS; t++) {
        const uint4* A = t ? A2 : A1;
        const uint4* Whi = Wfrag + (size_t)t * 4096;
        const uint4* Wlo = Whi + 2048;
        uint4 bvec[2][4];
#pragma unroll
        for (int nf = 0; nf < 2; nf++) {
            const uint4* row = A + (size_t)(nbase + nf * 16 + l16) * 16;
#pragma unroll
            for (int ks = 0; ks < 4; ks++) bvec[nf][ks] = row[ks * 4 + lg];
        }
#pragma unroll
        for (int ks = 0; ks < 4; ks++) {
            s8v b0 = __builtin_bit_cast(s8v, bvec[0][ks]);
            s8v b1 = __builtin_bit_cast(s8v, bvec[1][ks]);
#pragma unroll
            for (int df = 0; df < 8; df++) {
                int wi = (ks * 4 + lg) * 128 + df * 16 + l16;
                s8v ah = __builtin_bit_cast(s8v, Whi[wi]);
                s8v al = __builtin_bit_cast(s8v, Wlo[wi]);
                acc[0][df] = __builtin_amdgcn_mfma_f32_16x16x32_bf16(ah, b0, acc[0][df], 0, 0, 0);
                acc[1][df] = __builtin_amdgcn_mfma_f32_16x16x32_bf16(ah, b1, acc[1][df], 0, 0, 0);
                acc[0][df] = __builtin_amdgcn_mfma_f32_16x16x32_bf16(al, b0, acc[0][df], 0, 0, 0);
                acc[1][df] = __builtin_amdgcn_mfma_f32_16x16x32_bf16(al, b1, acc[1][df], 0, 0, 0);
            }
        }
    }

#pragma unroll
    for (int nf = 0; nf < 2; nf++) {
        int n = nbase + nf * 16 + l16;
        if (n < N) {
#pragma unroll
            for (int df = 0; df < 8; df++) {
                int d0 = df * 16 + lg * 4;
                const float4 bb = *reinterpret_cast<const float4*>(bias + d0);
                float4 o;
                o.x = fmaxf(acc[nf][df][0] + bb.x, 0.f);
                o.y = fmaxf(acc[nf][df][1] + bb.y, 0.f);
                o.z = fmaxf(acc[nf][df][2] + bb.z, 0.f);
                o.w = fmaxf(acc[nf][df][3] + bb.w, 0.f);
                if (F32OUT) {
                    *reinterpret_cast<float4*>(outF + (size_t)n * 384 + d0) = o;
                } else {
                    uint2 p;
                    p.x = pk2(o.x, o.y);
                    p.y = pk2(o.z, o.w);
                    *reinterpret_cast<uint2*>(outB + (size_t)n * 128 + d0) = p;
                }
            }
        }
    }
}

// ---------------- BatchNorm ----------------

template <bool BF16>
__global__ __launch_bounds__(256) void k_stats2(const void* __restrict__ in, int ldin, int N,
                                                float* __restrict__ gsum, float* __restrict__ gsq) {
    __shared__ float ss[16][16][8];
    __shared__ float sq[16][16][8];
    int c = threadIdx.x & 15, r = threadIdx.x >> 4;
    float s[8], q[8];
#pragma unroll
    for (int k = 0; k < 8; k++) { s[k] = 0.f; q[k] = 0.f; }
    for (int n = blockIdx.x * 16 + r; n < N; n += gridDim.x * 16) {
        float v[8];
        if (BF16) {
            unpack8(reinterpret_cast<const uint4*>(in)[(size_t)n * 16 + c], v);
        } else {
            const float* p = (const float*)in + (size_t)n * ldin + c * 8;
            float4 x0 = *reinterpret_cast<const float4*>(p);
            float4 x1 = *reinterpret_cast<const float4*>(p + 4);
            v[0] = x0.x; v[1] = x0.y; v[2] = x0.z; v[3] = x0.w;
            v[4] = x1.x; v[5] = x1.y; v[6] = x1.z; v[7] = x1.w;
        }
#pragma unroll
        for (int k = 0; k < 8; k++) { s[k] += v[k]; q[k] = fmaf(v[k], v[k], q[k]); }
    }
#pragma unroll
    for (int k = 0; k < 8; k++) { ss[r][c][k] = s[k]; sq[r][c][k] = q[k]; }
    __syncthreads();
    for (int off = 8; off > 0; off >>= 1) {
        if (r < off) {
#pragma unroll
            for (int k = 0; k < 8; k++) {
                ss[r][c][k] += ss[r + off][c][k];
                sq[r][c][k] += sq[r + off][c][k];
            }
        }
        __syncthreads();
    }
    if (r == 0) {
#pragma unroll
        for (int k = 0; k < 8; k++) {
            unsafeAtomicAdd(&gsum[c * 8 + k], ss[0][c][k]);
            unsafeAtomicAdd(&gsq[c * 8 + k], sq[0][c][k]);
        }
    }
}

__global__ void k_bnfin(const float* __restrict__ gsum, const float* __restrict__ gsq,
                        const float* __restrict__ gamma, const float* __restrict__ beta,
                        int N, float* __restrict__ a, float* __restrict__ c) {
    int d = threadIdx.x;  // 128
    float invN = 1.0f / (float)N;
    float mu = gsum[d] * invN;
    float var = gsq[d] * invN - mu * mu;
    float rs = rsqrtf(var + BN_EPS);
    float aa = gamma[d] * rs;
    a[d] = aa;
    c[d] = beta[d] - mu * aa;
}

// normalize: outF[n*384+f] = v*a[f]+c[f] ; optional compact bf16 copy
template <bool BF16IN>
__global__ void k_norm2(const void* __restrict__ in, int ldin,
                        const float* __restrict__ sa, const float* __restrict__ sc,
                        float* __restrict__ outF, uint4* __restrict__ outB, int N) {
    int idx = blockIdx.x * 256 + threadIdx.x;
    if (idx >= N * 16) return;
    int n = idx >> 4, cc = idx & 15;
    float v[8];
    if (BF16IN) {
        unpack8(reinterpret_cast<const uint4*>(in)[(size_t)n * 16 + cc], v);
    } else {
        const float* p = (const float*)in + (size_t)n * ldin + cc * 8;
        float4 x0 = *reinterpret_cast<const float4*>(p);
        float4 x1 = *reinterpret_cast<const float4*>(p + 4);
        v[0] = x0.x; v[1] = x0.y; v[2] = x0.z; v[3] = x0.w;
        v[4] = x1.x; v[5] = x1.y; v[6] = x1.z; v[7] = x1.w;
    }
    const float4 a0 = *reinterpret_cast<const float4*>(sa + cc * 8);
    const float4 a1 = *reinterpret_cast<const float4*>(sa + cc * 8 + 4);
    const float4 c0 = *reinterpret_cast<const float4*>(sc + cc * 8);
    const float4 c1 = *reinterpret_cast<const float4*>(sc + cc * 8 + 4);
    float y[8];
    y[0] = fmaf(v[0], a0.x, c0.x); y[1] = fmaf(v[1], a0.y, c0.y);
    y[2] = fmaf(v[2], a0.z, c0.z); y[3] = fmaf(v[3], a0.w, c0.w);
    y[4] = fmaf(v[4], a1.x, c1.x); y[5] = fmaf(v[5], a1.y, c1.y);
    y[6] = fmaf(v[6], a1.z, c1.z); y[7] = fmaf(v[7], a1.w, c1.w);
    float* po = outF + (size_t)n * 384 + cc * 8;
    *reinterpret_cast<float4*>(po) = make_float4(y[0], y[1], y[2], y[3]);
    *reinterpret_cast<float4*>(po + 4) = make_float4(y[4], y[5], y[6], y[7]);
    if (outB) {
        uint4 o;
        o.x = pk2(y[0], y[1]); o.y = pk2(y[2], y[3]);
        o.z = pk2(y[4], y[5]); o.w = pk2(y[6], y[7]);
        outB[(size_t)n * 16 + cc] = o;
    }
}

// ---------------- pooling ----------------

__device__ __forceinline__ int lbound(const int* __restrict__ b, int n, int v) {
    int lo = 0, hi = n;
    while (lo < hi) {
        int m = (lo + hi) >> 1;
        if (b[m] < v) lo = m + 1; else hi = m;
    }
    return lo;
}

__global__ void k_pool(const float* __restrict__ nf, const int* __restrict__ batch,
                       int N, float* __restrict__ out) {
    int g = blockIdx.x;
    int d = threadIdx.x;  // 384
    int lo = lbound(batch, N, g);
    int hi = lbound(batch, N, g + 1);
    float s = 0.f;
    for (int n = lo; n < hi; n++) s += nf[(size_t)n * 384 + d];
    out[(size_t)g * 384 + d] = s;
}

// ---------------- launch ----------------

extern "C" void kernel_launch(void* const* d_in, const int* in_sizes, int n_in,
                              void* d_out, int out_size, void* d_ws, size_t ws_size,
                              hipStream_t stream) {
    const float* x   = (const float*)d_in[0];
    const int*   ei  = (const int*)d_in[1];
    const int*   bat = (const int*)d_in[2];
    const float* sWl = (const float*)d_in[3];
    const float* sbl = (const float*)d_in[4];
    const float* sWr = (const float*)d_in[5];
    const float* gW1 = (const float*)d_in[6];
    const float* gb1 = (const float*)d_in[7];
    const float* gW2 = (const float*)d_in[8];
    const float* gb2 = (const float*)d_in[9];
    const float* bng = (const float*)d_in[10];
    const float* bnb = (const float*)d_in[11];

    const int N = in_sizes[0] / 128;
    const int E = in_sizes[1] / 2;
    const int G = out_size / 384 - N;
    const int* srcp = ei;
    const int* dstp = ei + E;

    char* w = (char*)d_ws;
    auto alloc = [&](size_t bytes) -> void* {
        void* p = (void*)w;
        w += (bytes + 255) & ~(size_t)255;
        return p;
    };
    const size_t Npad = (size_t)(N + 128);
    int*   rp    = (int*)alloc(((size_t)N + 1) * 4);
    int*   csr   = (int*)alloc((size_t)E * 4);
    int*   bcnt  = (int*)alloc(8192);
    int*   bbase = (int*)alloc(8192);
    float* gsum  = (float*)alloc(512);
    float* gsq   = (float*)alloc(512);      // contiguous with gsum
    float* abuf  = (float*)alloc(512);
    float* cbuf  = (float*)alloc(512);
    // 6 weights x (hi plane + lo plane) x 16384 bf16
    unsigned short* Wp = (unsigned short*)alloc((size_t)6 * 2 * 16384 * 2);
    unsigned short* ab = (unsigned short*)alloc(Npad * 256);  // bf16 [N][128]
    unsigned short* tb = (unsigned short*)alloc(Npad * 256);  // bf16 [N][128]

    float* pooled = (float*)d_out;                 // [G][384]
    float* nf     = pooled + (size_t)G * 384;      // [N][384]

    // bucket geometry (bucket = dst >> 8)
    const int NB  = (N + 255) / 256;
    int CAP = ((2 * (E / (NB > 0 ? NB : 1)) + 511) / 512) * 512;
    const long long maxcap = (long long)(Npad * 256) / ((long long)NB * 8);
    if ((long long)CAP > maxcap) CAP = (int)(maxcap & ~511LL);
    unsigned long long* ebuf = (unsigned long long*)ab;  // aliases ab (free now)

    const int egrid = (E + EPB - 1) / EPB;
    const int agrid = (N + 15) / 16;
    const int ggrid = (N + 127) / 128;
    const int vgrid = (N * 16 + 255) / 256;

    // ---- CSR build (binned) ----
    hipMemsetAsync(bcnt, 0, (size_t)NB * 4, stream);
    k_binA<<<egrid, 256, 0, stream>>>(srcp, dstp, E, NB, CAP, bcnt, ebuf);
    k_bscan<<<1, 256, 0, stream>>>(bcnt, NB, bbase);
    k_binB<<<NB, 256, 0, stream>>>(ebuf, CAP, bcnt, bbase, N, E, rp, csr);

    // ---- prep: x -> bf16 (in tb), pack weights (hi+lo planes) ----
    k_cvt_bf16<<<vgrid, 256, 0, stream>>>(x, (uint4*)tb, N * 16);
    k_pack_w<<<64, 256, 0, stream>>>(sWl,         Wp + 0 * 32768);
    k_pack_w<<<64, 256, 0, stream>>>(sWr,         Wp + 1 * 32768);
    k_pack_w<<<64, 256, 0, stream>>>(gW1,         Wp + 2 * 32768);
    k_pack_w<<<64, 256, 0, stream>>>(gW2,         Wp + 3 * 32768);
    k_pack_w<<<64, 256, 0, stream>>>(gW1 + 16384, Wp + 4 * 32768);
    k_pack_w<<<64, 256, 0, stream>>>(gW2 + 16384, Wp + 5 * 32768);

    // ---- Layer 0: SAGE ----
    k_aggr<false, true><<<agrid, 256, 0, stream>>>(rp, csr, (const uint4*)tb, (uint4*)ab, N);
    // h0(pre-BN, relu'd) = relu(aggr@Wl + bl + x@Wr) -> nf slice 0 (f32)
    k_gemm_mfma<2, true><<<ggrid, 256, 0, stream>>>(
        (const uint4*)ab, (const uint4*)tb, (const uint4*)Wp, sbl, nf, nullptr, N);
    hipMemsetAsync(gsum, 0, 1024, stream);
    k_stats2<false><<<512, 256, 0, stream>>>(nf, 384, N, gsum, gsq);
    k_bnfin<<<1, 128, 0, stream>>>(gsum, gsq, bng, bnb, N, abuf, cbuf);
    k_norm2<false><<<vgrid, 256, 0, stream>>>(nf, 384, abuf, cbuf, nf, (uint4*)tb, N);

    // ---- Layers 1,2: GIN ----
    for (int l = 1; l < 3; l++) {
        const uint4* W1p = (const uint4*)(Wp + (size_t)(2 + (l - 1) * 2) * 32768);
        const uint4* W2p = (const uint4*)(Wp + (size_t)(3 + (l - 1) * 2) * 32768);
        const float* b1 = gb1 + (size_t)(l - 1) * 128;
        const float* b2 = gb2 + (size_t)(l - 1) * 128;
        float* nfl = nf + (size_t)l * 128;

        // ab = h + sum_nb h  (gather from tb)
        k_aggr<true, false><<<agrid, 256, 0, stream>>>(rp, csr, (const uint4*)tb, (uint4*)ab, N);
        // t = relu(ab@W1 + b1) -> tb (bf16)
        k_gemm_mfma<1, false><<<ggrid, 256, 0, stream>>>(
            (const uint4*)ab, nullptr, W1p, b1, nullptr, tb, N);
        // u = relu(t@W2 + b2) -> nf slice l (f32, stride 384) — stays f32 thru BN
        k_gemm_mfma<1, true><<<ggrid, 256, 0, stream>>>(
            (const uint4*)tb, nullptr, W2p, b2, nfl, nullptr, N);
        hipMemsetAsync(gsum, 0, 1024, stream);
        k_stats2<false><<<512, 256, 0, stream>>>(nfl, 384, N, gsum, gsq);
        k_bnfin<<<1, 128, 0, stream>>>(gsum, gsq, bng + l * 128, bnb + l * 128, N, abuf, cbuf);
        // normalize in place (f32) + compact bf16 h_l -> tb (only needed for l=1)
        k_norm2<false><<<vgrid, 256, 0, stream>>>(nfl, 384, abuf, cbuf, nfl,
                                                  (l < 2) ? (uint4*)tb : nullptr, N);
    }

    // ---- pooling ----
    k_pool<<<G, 384, 0, stream>>>(nf, bat, N, pooled);
}

// Round 6
// 669.762 us; speedup vs baseline: 1.6439x; 1.4681x over previous
//
#include <hip/hip_runtime.h>
#include <hip/hip_bf16.h>

// ---------------------------------------------------------------------------
// GNN encoder: SAGEConv -> BN -> 2x (GINConv -> BN), concat outputs + add-pool
// N=100000, E=1600000, F=D=128, L=3, G=500
// Round 6: BN stats fused into GEMM epilogue (kills 3x107us latency-bound
// k_stats2). Binned CSR; bf16 gather tables; hi/lo-split bf16 MFMA GEMMs.
// ---------------------------------------------------------------------------

#define BN_EPS 1e-5f
#define EPB 4096   // edges per block in bin pass A

typedef short s8v __attribute__((ext_vector_type(8)));
typedef float f4v __attribute__((ext_vector_type(4)));

__device__ __forceinline__ float bflo(unsigned u) { return __uint_as_float(u << 16); }
__device__ __forceinline__ float bfhi(unsigned u) { return __uint_as_float(u & 0xffff0000u); }
__device__ __forceinline__ unsigned short f2bf(float f) {
    unsigned u = __float_as_uint(f);
    unsigned r = (u + 0x7fffu + ((u >> 16) & 1u)) >> 16;  // RTNE
    return (unsigned short)r;
}
__device__ __forceinline__ unsigned pk2(float a, float b) {
    return (unsigned)f2bf(a) | ((unsigned)f2bf(b) << 16);
}
__device__ __forceinline__ void unpack8(uint4 u, float* v) {
    v[0] = bflo(u.x); v[1] = bfhi(u.x);
    v[2] = bflo(u.y); v[3] = bfhi(u.y);
    v[4] = bflo(u.z); v[5] = bfhi(u.z);
    v[6] = bflo(u.w); v[7] = bfhi(u.w);
}

// ---------------- CSR build (binned, 2-pass) ----------------

__global__ __launch_bounds__(256) void k_binA(const int* __restrict__ src,
                                              const int* __restrict__ dst, int E, int NB, int CAP,
                                              int* __restrict__ bcnt,
                                              unsigned long long* __restrict__ ebuf) {
    __shared__ int hist[512], base[512], cur[512];
    const int tid = threadIdx.x;
    const int e0 = blockIdx.x * EPB;
    for (int i = tid; i < 512; i += 256) { hist[i] = 0; cur[i] = 0; }
    __syncthreads();
#pragma unroll
    for (int k = 0; k < EPB / 256; k++) {
        int e = e0 + k * 256 + tid;
        if (e < E) atomicAdd(&hist[dst[e] >> 8], 1);
    }
    __syncthreads();
    for (int b = tid; b < NB; b += 256)
        base[b] = hist[b] ? atomicAdd(&bcnt[b], hist[b]) : 0;
    __syncthreads();
#pragma unroll
    for (int k = 0; k < EPB / 256; k++) {
        int e = e0 + k * 256 + tid;
        if (e < E) {
            int d = dst[e];
            int b = d >> 8;
            int lp = atomicAdd(&cur[b], 1);
            int gp = base[b] + lp;
            if (gp < CAP)
                ebuf[(size_t)b * CAP + gp] = ((unsigned long long)d << 32) | (unsigned)src[e];
        }
    }
}

__global__ void k_bscan(const int* __restrict__ bcnt, int NB, int* __restrict__ bbase) {
    __shared__ int sm[256];
    const int tid = threadIdx.x;
    const int c = (NB + 255) / 256;
    int s = 0;
    for (int k = 0; k < c; k++) { int i = tid * c + k; if (i < NB) s += bcnt[i]; }
    sm[tid] = s;
    __syncthreads();
    for (int off = 1; off < 256; off <<= 1) {
        int v = (tid >= off) ? sm[tid - off] : 0;
        __syncthreads();
        sm[tid] += v;
        __syncthreads();
    }
    int run = sm[tid] - s;
    for (int k = 0; k < c; k++) {
        int i = tid * c + k;
        if (i < NB) { bbase[i] = run; run += bcnt[i]; }
    }
}

__global__ __launch_bounds__(256) void k_binB(const unsigned long long* __restrict__ ebuf,
                                              int CAP, const int* __restrict__ bcnt,
                                              const int* __restrict__ bbase,
                                              int N, int E,
                                              int* __restrict__ rp, int* __restrict__ csr) {
    __shared__ int deg[256], sc[256], cur[256];
    const int tid = threadIdx.x;
    const int b = blockIdx.x;
    const int cnt = min(bcnt[b], CAP);
    const int cbase = bbase[b];
    deg[tid] = 0;
    __syncthreads();
    const unsigned long long* eb = ebuf + (size_t)b * CAP;
    for (int i = tid; i < cnt; i += 256) {
        int d = (int)(eb[i] >> 32);
        atomicAdd(&deg[d & 255], 1);
    }
    __syncthreads();
    int myDeg = deg[tid];
    sc[tid] = myDeg;
    __syncthreads();
    for (int off = 1; off < 256; off <<= 1) {
        int v = (tid >= off) ? sc[tid - off] : 0;
        __syncthreads();
        sc[tid] += v;
        __syncthreads();
    }
    int pos = cbase + sc[tid] - myDeg;
    int node = b * 256 + tid;
    if (node < N) rp[node] = pos;
    cur[tid] = pos;
    __syncthreads();
    for (int i = tid; i < cnt; i += 256) {
        unsigned long long e = eb[i];
        int d = (int)(e >> 32);
        int p = atomicAdd(&cur[d & 255], 1);
        csr[p] = (int)(e & 0xffffffffu);
    }
    if (b == 0 && tid == 0) rp[N] = E;
}

// ---------------- conversions / weight packing ----------------

__global__ void k_cvt_bf16(const float* __restrict__ in, uint4* __restrict__ out, int n8) {
    int i = blockIdx.x * 256 + threadIdx.x;
    if (i >= n8) return;
    const float4* p = reinterpret_cast<const float4*>(in) + (size_t)i * 2;
    float4 a = p[0], b = p[1];
    uint4 o;
    o.x = pk2(a.x, a.y); o.y = pk2(a.z, a.w);
    o.z = pk2(b.x, b.y); o.w = pk2(b.z, b.w);
    out[i] = o;
}

// pack one 128x128 f32 W into MFMA A-operand (W^T) fragment layout, split into
// bf16 hi plane (+0) and bf16 lo-residual plane (+16384)
__global__ void k_pack_w(const float* __restrict__ W, unsigned short* __restrict__ out) {
    int idx = blockIdx.x * 256 + threadIdx.x;  // 16384
    int k = idx >> 7, d = idx & 127;
    float w = W[idx];
    unsigned short h = f2bf(w);
    float hf = __uint_as_float((unsigned)h << 16);
    unsigned short l = f2bf(w - hf);
    int o = (((k >> 3) * 128) + d) * 8 + (k & 7);
    out[o] = h;
    out[16384 + o] = l;
}

// ---------------- aggregation (bf16 src rows, 16 lanes x 16B per node) -----

template <bool SELF, bool MEAN>
__global__ void k_aggr(const int* __restrict__ rp, const int* __restrict__ csr,
                       const uint4* __restrict__ src, uint4* __restrict__ out, int N) {
    int node = blockIdx.x * 16 + (threadIdx.x >> 4);
    if (node >= N) return;
    int c = threadIdx.x & 15;
    float acc[8];
    if (SELF) {
        unpack8(src[(size_t)node * 16 + c], acc);
    } else {
#pragma unroll
        for (int k = 0; k < 8; k++) acc[k] = 0.f;
    }
    int lo = rp[node], hi = rp[node + 1];
    for (int j = lo; j < hi; j++) {
        int sn = csr[j];
        float v[8];
        unpack8(src[(size_t)sn * 16 + c], v);
#pragma unroll
        for (int k = 0; k < 8; k++) acc[k] += v[k];
    }
    if (MEAN) {
        float inv = 1.0f / fmaxf((float)(hi - lo), 1.0f);
#pragma unroll
        for (int k = 0; k < 8; k++) acc[k] *= inv;
    }
    uint4 o;
    o.x = pk2(acc[0], acc[1]); o.y = pk2(acc[2], acc[3]);
    o.z = pk2(acc[4], acc[5]); o.w = pk2(acc[6], acc[7]);
    out[(size_t)node * 16 + c] = o;
}

// ---------------- MFMA GEMM (+ fused BN stats) ----------------
// C = relu( sum_t A_t @ (Whi_t + Wlo_t) + bias ), A_t: [N x 128] bf16 rows.
// Swapped operands: mfma(A_op = W^T frag, B_op = node frag) -> C^T frags,
// lane holds node = l16, d = df*16 + lg*4 + reg. W streamed from L2, no LDS.
// STATS: per-block per-channel sum/sumsq -> shfl reduce over node-lanes ->
// LDS cross-wave -> 1 atomic per channel per block.

template <int TERMS, bool F32OUT, bool STATS>
__global__ __launch_bounds__(256) void k_gemm_mfma(
    const uint4* __restrict__ A1, const uint4* __restrict__ A2,
    const uint4* __restrict__ Wfrag,  // TERMS * 2 * 2048 uint4: [term][hi,lo]
    const float* __restrict__ bias,
    float* __restrict__ outF,                 // if F32OUT: stride 384
    unsigned short* __restrict__ outB,        // else: compact bf16 [N][128]
    float* __restrict__ gsum, float* __restrict__ gsq,
    int N) {
    __shared__ float sred[4][128][2];
    const int tid = threadIdx.x;
    const int lane = tid & 63, wid = tid >> 6;
    const int nbase = blockIdx.x * 128 + wid * 32;
    const int l16 = lane & 15, lg = lane >> 4;

    f4v acc[2][8];
#pragma unroll
    for (int nf = 0; nf < 2; nf++)
#pragma unroll
        for (int df = 0; df < 8; df++) {
            acc[nf][df][0] = 0.f; acc[nf][df][1] = 0.f;
            acc[nf][df][2] = 0.f; acc[nf][df][3] = 0.f;
        }

#pragma unroll
    for (int t = 0; t < TERMS; t++) {
        const uint4* A = t ? A2 : A1;
        const uint4* Whi = Wfrag + (size_t)t * 4096;
        const uint4* Wlo = Whi + 2048;
        uint4 bvec[2][4];
#pragma unroll
        for (int nf = 0; nf < 2; nf++) {
            const uint4* row = A + (size_t)(nbase + nf * 16 + l16) * 16;
#pragma unroll
            for (int ks = 0; ks < 4; ks++) bvec[nf][ks] = row[ks * 4 + lg];
        }
#pragma unroll
        for (int ks = 0; ks < 4; ks++) {
            s8v b0 = __builtin_bit_cast(s8v, bvec[0][ks]);
            s8v b1 = __builtin_bit_cast(s8v, bvec[1][ks]);
#pragma unroll
            for (int df = 0; df < 8; df++) {
                int wi = (ks * 4 + lg) * 128 + df * 16 + l16;
                s8v ah = __builtin_bit_cast(s8v, Whi[wi]);
                s8v al = __builtin_bit_cast(s8v, Wlo[wi]);
                acc[0][df] = __builtin_amdgcn_mfma_f32_16x16x32_bf16(ah, b0, acc[0][df], 0, 0, 0);
                acc[1][df] = __builtin_amdgcn_mfma_f32_16x16x32_bf16(ah, b1, acc[1][df], 0, 0, 0);
                acc[0][df] = __builtin_amdgcn_mfma_f32_16x16x32_bf16(al, b0, acc[0][df], 0, 0, 0);
                acc[1][df] = __builtin_amdgcn_mfma_f32_16x16x32_bf16(al, b1, acc[1][df], 0, 0, 0);
            }
        }
    }

    // bias + relu (keep in regs for both store and stats)
    const bool v0 = (nbase + 0 * 16 + l16) < N;
    const bool v1 = (nbase + 1 * 16 + l16) < N;
    float4 oo[2][8];
#pragma unroll
    for (int df = 0; df < 8; df++) {
        int d0 = df * 16 + lg * 4;
        const float4 bb = *reinterpret_cast<const float4*>(bias + d0);
#pragma unroll
        for (int nf = 0; nf < 2; nf++) {
            oo[nf][df].x = fmaxf(acc[nf][df][0] + bb.x, 0.f);
            oo[nf][df].y = fmaxf(acc[nf][df][1] + bb.y, 0.f);
            oo[nf][df].z = fmaxf(acc[nf][df][2] + bb.z, 0.f);
            oo[nf][df].w = fmaxf(acc[nf][df][3] + bb.w, 0.f);
        }
    }

    if (STATS) {
#pragma unroll
        for (int df = 0; df < 8; df++) {
            float s[4], q[4];
#pragma unroll
            for (int r = 0; r < 4; r++) {
                float a0 = v0 ? (&oo[0][df].x)[r] : 0.f;
                float a1 = v1 ? (&oo[1][df].x)[r] : 0.f;
                s[r] = a0 + a1;
                q[r] = a0 * a0 + a1 * a1;
            }
#pragma unroll
            for (int m = 1; m < 16; m <<= 1) {
#pragma unroll
                for (int r = 0; r < 4; r++) {
                    s[r] += __shfl_xor(s[r], m, 64);
                    q[r] += __shfl_xor(q[r], m, 64);
                }
            }
            if (l16 == 0) {
#pragma unroll
                for (int r = 0; r < 4; r++) {
                    sred[wid][df * 16 + lg * 4 + r][0] = s[r];
                    sred[wid][df * 16 + lg * 4 + r][1] = q[r];
                }
            }
        }
        __syncthreads();
        if (tid < 128) {
            float s = sred[0][tid][0] + sred[1][tid][0] + sred[2][tid][0] + sred[3][tid][0];
            float q = sred[0][tid][1] + sred[1][tid][1] + sred[2][tid][1] + sred[3][tid][1];
            unsafeAtomicAdd(&gsum[tid], s);
            unsafeAtomicAdd(&gsq[tid], q);
        }
    }

#pragma unroll
    for (int nf = 0; nf < 2; nf++) {
        int n = nbase + nf * 16 + l16;
        if (n < N) {
#pragma unroll
            for (int df = 0; df < 8; df++) {
                int d0 = df * 16 + lg * 4;
                if (F32OUT) {
                    *reinterpret_cast<float4*>(outF + (size_t)n * 384 + d0) = oo[nf][df];
                } else {
                    uint2 p;
                    p.x = pk2(oo[nf][df].x, oo[nf][df].y);
                    p.y = pk2(oo[nf][df].z, oo[nf][df].w);
                    *reinterpret_cast<uint2*>(outB + (size_t)n * 128 + d0) = p;
                }
            }
        }
    }
}

// ---------------- BatchNorm finalize / normalize ----------------

__global__ void k_bnfin(const float* __restrict__ gsum, const float* __restrict__ gsq,
                        const float* __restrict__ gamma, const float* __restrict__ beta,
                        int N, float* __restrict__ a, float* __restrict__ c) {
    int d = threadIdx.x;  // 128
    float invN = 1.0f / (float)N;
    float mu = gsum[d] * invN;
    float var = gsq[d] * invN - mu * mu;
    float rs = rsqrtf(var + BN_EPS);
    float aa = gamma[d] * rs;
    a[d] = aa;
    c[d] = beta[d] - mu * aa;
}

// normalize: outF[n*384+f] = v*a[f]+c[f] ; optional compact bf16 copy
template <bool BF16IN>
__global__ void k_norm2(const void* __restrict__ in, int ldin,
                        const float* __restrict__ sa, const float* __restrict__ sc,
                        float* __restrict__ outF, uint4* __restrict__ outB, int N) {
    int idx = blockIdx.x * 256 + threadIdx.x;
    if (idx >= N * 16) return;
    int n = idx >> 4, cc = idx & 15;
    float v[8];
    if (BF16IN) {
        unpack8(reinterpret_cast<const uint4*>(in)[(size_t)n * 16 + cc], v);
    } else {
        const float* p = (const float*)in + (size_t)n * ldin + cc * 8;
        float4 x0 = *reinterpret_cast<const float4*>(p);
        float4 x1 = *reinterpret_cast<const float4*>(p + 4);
        v[0] = x0.x; v[1] = x0.y; v[2] = x0.z; v[3] = x0.w;
        v[4] = x1.x; v[5] = x1.y; v[6] = x1.z; v[7] = x1.w;
    }
    const float4 a0 = *reinterpret_cast<const float4*>(sa + cc * 8);
    const float4 a1 = *reinterpret_cast<const float4*>(sa + cc * 8 + 4);
    const float4 c0 = *reinterpret_cast<const float4*>(sc + cc * 8);
    const float4 c1 = *reinterpret_cast<const float4*>(sc + cc * 8 + 4);
    float y[8];
    y[0] = fmaf(v[0], a0.x, c0.x); y[1] = fmaf(v[1], a0.y, c0.y);
    y[2] = fmaf(v[2], a0.z, c0.z); y[3] = fmaf(v[3], a0.w, c0.w);
    y[4] = fmaf(v[4], a1.x, c1.x); y[5] = fmaf(v[5], a1.y, c1.y);
    y[6] = fmaf(v[6], a1.z, c1.z); y[7] = fmaf(v[7], a1.w, c1.w);
    float* po = outF + (size_t)n * 384 + cc * 8;
    *reinterpret_cast<float4*>(po) = make_float4(y[0], y[1], y[2], y[3]);
    *reinterpret_cast<float4*>(po + 4) = make_float4(y[4], y[5], y[6], y[7]);
    if (outB) {
        uint4 o;
        o.x = pk2(y[0], y[1]); o.y = pk2(y[2], y[3]);
        o.z = pk2(y[4], y[5]); o.w = pk2(y[6], y[7]);
        outB[(size_t)n * 16 + cc] = o;
    }
}

// ---------------- pooling ----------------

__device__ __forceinline__ int lbound(const int* __restrict__ b, int n, int v) {
    int lo = 0, hi = n;
    while (lo < hi) {
        int m = (lo + hi) >> 1;
        if (b[m] < v) lo = m + 1; else hi = m;
    }
    return lo;
}

__global__ void k_pool(const float* __restrict__ nf, const int* __restrict__ batch,
                       int N, float* __restrict__ out) {
    int g = blockIdx.x;
    int d = threadIdx.x;  // 384
    int lo = lbound(batch, N, g);
    int hi = lbound(batch, N, g + 1);
    float s = 0.f;
    for (int n = lo; n < hi; n++) s += nf[(size_t)n * 384 + d];
    out[(size_t)g * 384 + d] = s;
}

// ---------------- launch ----------------

extern "C" void kernel_launch(void* const* d_in, const int* in_sizes, int n_in,
                              void* d_out, int out_size, void* d_ws, size_t ws_size,
                              hipStream_t stream) {
    const float* x   = (const float*)d_in[0];
    const int*   ei  = (const int*)d_in[1];
    const int*   bat = (const int*)d_in[2];
    const float* sWl = (const float*)d_in[3];
    const float* sbl = (const float*)d_in[4];
    const float* sWr = (const float*)d_in[5];
    const float* gW1 = (const float*)d_in[6];
    const float* gb1 = (const float*)d_in[7];
    const float* gW2 = (const float*)d_in[8];
    const float* gb2 = (const float*)d_in[9];
    const float* bng = (const float*)d_in[10];
    const float* bnb = (const float*)d_in[11];

    const int N = in_sizes[0] / 128;
    const int E = in_sizes[1] / 2;
    const int G = out_size / 384 - N;
    const int* srcp = ei;
    const int* dstp = ei + E;

    char* w = (char*)d_ws;
    auto alloc = [&](size_t bytes) -> void* {
        void* p = (void*)w;
        w += (bytes + 255) & ~(size_t)255;
        return p;
    };
    const size_t Npad = (size_t)(N + 128);
    int*   rp    = (int*)alloc(((size_t)N + 1) * 4);
    int*   csr   = (int*)alloc((size_t)E * 4);
    int*   bcnt  = (int*)alloc(8192);
    int*   bbase = (int*)alloc(8192);
    float* gsum  = (float*)alloc(512);
    float* gsq   = (float*)alloc(512);      // contiguous with gsum
    float* abuf  = (float*)alloc(512);
    float* cbuf  = (float*)alloc(512);
    // 6 weights x (hi plane + lo plane) x 16384 bf16
    unsigned short* Wp = (unsigned short*)alloc((size_t)6 * 2 * 16384 * 2);
    unsigned short* ab = (unsigned short*)alloc(Npad * 256);  // bf16 [N][128]
    unsigned short* tb = (unsigned short*)alloc(Npad * 256);  // bf16 [N][128]

    float* pooled = (float*)d_out;                 // [G][384]
    float* nf     = pooled + (size_t)G * 384;      // [N][384]

    // bucket geometry (bucket = dst >> 8)
    const int NB  = (N + 255) / 256;
    int CAP = ((2 * (E / (NB > 0 ? NB : 1)) + 511) / 512) * 512;
    const long long maxcap = (long long)(Npad * 256) / ((long long)NB * 8);
    if ((long long)CAP > maxcap) CAP = (int)(maxcap & ~511LL);
    unsigned long long* ebuf = (unsigned long long*)ab;  // aliases ab (free now)

    const int egrid = (E + EPB - 1) / EPB;
    const int agrid = (N + 15) / 16;
    const int ggrid = (N + 127) / 128;
    const int vgrid = (N * 16 + 255) / 256;

    // ---- CSR build (binned) ----
    hipMemsetAsync(bcnt, 0, (size_t)NB * 4, stream);
    k_binA<<<egrid, 256, 0, stream>>>(srcp, dstp, E, NB, CAP, bcnt, ebuf);
    k_bscan<<<1, 256, 0, stream>>>(bcnt, NB, bbase);
    k_binB<<<NB, 256, 0, stream>>>(ebuf, CAP, bcnt, bbase, N, E, rp, csr);

    // ---- prep: x -> bf16 (in tb), pack weights (hi+lo planes) ----
    k_cvt_bf16<<<vgrid, 256, 0, stream>>>(x, (uint4*)tb, N * 16);
    k_pack_w<<<64, 256, 0, stream>>>(sWl,         Wp + 0 * 32768);
    k_pack_w<<<64, 256, 0, stream>>>(sWr,         Wp + 1 * 32768);
    k_pack_w<<<64, 256, 0, stream>>>(gW1,         Wp + 2 * 32768);
    k_pack_w<<<64, 256, 0, stream>>>(gW2,         Wp + 3 * 32768);
    k_pack_w<<<64, 256, 0, stream>>>(gW1 + 16384, Wp + 4 * 32768);
    k_pack_w<<<64, 256, 0, stream>>>(gW2 + 16384, Wp + 5 * 32768);

    // ---- Layer 0: SAGE ----
    k_aggr<false, true><<<agrid, 256, 0, stream>>>(rp, csr, (const uint4*)tb, (uint4*)ab, N);
    hipMemsetAsync(gsum, 0, 1024, stream);
    // h0(pre-BN, relu'd) = relu(aggr@Wl + bl + x@Wr) -> nf slice 0 (f32) + stats
    k_gemm_mfma<2, true, true><<<ggrid, 256, 0, stream>>>(
        (const uint4*)ab, (const uint4*)tb, (const uint4*)Wp, sbl, nf, nullptr,
        gsum, gsq, N);
    k_bnfin<<<1, 128, 0, stream>>>(gsum, gsq, bng, bnb, N, abuf, cbuf);
    k_norm2<false><<<vgrid, 256, 0, stream>>>(nf, 384, abuf, cbuf, nf, (uint4*)tb, N);

    // ---- Layers 1,2: GIN ----
    for (int l = 1; l < 3; l++) {
        const uint4* W1p = (const uint4*)(Wp + (size_t)(2 + (l - 1) * 2) * 32768);
        const uint4* W2p = (const uint4*)(Wp + (size_t)(3 + (l - 1) * 2) * 32768);
        const float* b1 = gb1 + (size_t)(l - 1) * 128;
        const float* b2 = gb2 + (size_t)(l - 1) * 128;
        float* nfl = nf + (size_t)l * 128;

        // ab = h + sum_nb h  (gather from tb)
        k_aggr<true, false><<<agrid, 256, 0, stream>>>(rp, csr, (const uint4*)tb, (uint4*)ab, N);
        // t = relu(ab@W1 + b1) -> tb (bf16), no stats
        k_gemm_mfma<1, false, false><<<ggrid, 256, 0, stream>>>(
            (const uint4*)ab, nullptr, W1p, b1, nullptr, tb, nullptr, nullptr, N);
        hipMemsetAsync(gsum, 0, 1024, stream);
        // u = relu(t@W2 + b2) -> nf slice l (f32) + stats
        k_gemm_mfma<1, true, true><<<ggrid, 256, 0, stream>>>(
            (const uint4*)tb, nullptr, W2p, b2, nfl, nullptr, gsum, gsq, N);
        k_bnfin<<<1, 128, 0, stream>>>(gsum, gsq, bng + l * 128, bnb + l * 128, N, abuf, cbuf);
        // normalize in place (f32) + compact bf16 h_l -> tb (only needed for l=1)
        k_norm2<false><<<vgrid, 256, 0, stream>>>(nfl, 384, abuf, cbuf, nfl,
                                                  (l < 2) ? (uint4*)tb : nullptr, N);
    }

    // ---- pooling ----
    k_pool<<<G, 384, 0, stream>>>(nf, bat, N, pooled);
}

// Round 8
// 620.928 us; speedup vs baseline: 1.7732x; 1.0786x over previous
//
#include <hip/hip_runtime.h>
#include <hip/hip_bf16.h>

// ---------------------------------------------------------------------------
// GNN encoder: SAGEConv -> BN -> 2x (GINConv -> BN), concat outputs + add-pool
// N=100000, E=1600000, F=D=128, L=3, G=500
// Round 8: round-6 numerics (h rounded AFTER normalization — BN fold reverted)
// + fused GIN MLP (t,u in one kernel via swizzled LDS t-tile)
// + k_cvt_h (bf16 h table only) + fused normalize+pool finale.
// ---------------------------------------------------------------------------

#define BN_EPS 1e-5f
#define EPB 4096   // edges per block in bin pass A

typedef short s8v __attribute__((ext_vector_type(8)));
typedef float f4v __attribute__((ext_vector_type(4)));

__device__ __forceinline__ float bflo(unsigned u) { return __uint_as_float(u << 16); }
__device__ __forceinline__ float bfhi(unsigned u) { return __uint_as_float(u & 0xffff0000u); }
__device__ __forceinline__ unsigned short f2bf(float f) {
    unsigned u = __float_as_uint(f);
    unsigned r = (u + 0x7fffu + ((u >> 16) & 1u)) >> 16;  // RTNE
    return (unsigned short)r;
}
__device__ __forceinline__ unsigned pk2(float a, float b) {
    return (unsigned)f2bf(a) | ((unsigned)f2bf(b) << 16);
}
__device__ __forceinline__ void unpack8(uint4 u, float* v) {
    v[0] = bflo(u.x); v[1] = bfhi(u.x);
    v[2] = bflo(u.y); v[3] = bfhi(u.y);
    v[4] = bflo(u.z); v[5] = bfhi(u.z);
    v[6] = bflo(u.w); v[7] = bfhi(u.w);
}

// ---------------- CSR build (binned, 2-pass) ----------------

__global__ __launch_bounds__(256) void k_binA(const int* __restrict__ src,
                                              const int* __restrict__ dst, int E, int NB, int CAP,
                                              int* __restrict__ bcnt,
                                              unsigned long long* __restrict__ ebuf) {
    __shared__ int hist[512], base[512], cur[512];
    const int tid = threadIdx.x;
    const int e0 = blockIdx.x * EPB;
    for (int i = tid; i < 512; i += 256) { hist[i] = 0; cur[i] = 0; }
    __syncthreads();
#pragma unroll
    for (int k = 0; k < EPB / 256; k++) {
        int e = e0 + k * 256 + tid;
        if (e < E) atomicAdd(&hist[dst[e] >> 8], 1);
    }
    __syncthreads();
    for (int b = tid; b < NB; b += 256)
        base[b] = hist[b] ? atomicAdd(&bcnt[b], hist[b]) : 0;
    __syncthreads();
#pragma unroll
    for (int k = 0; k < EPB / 256; k++) {
        int e = e0 + k * 256 + tid;
        if (e < E) {
            int d = dst[e];
            int b = d >> 8;
            int lp = atomicAdd(&cur[b], 1);
            int gp = base[b] + lp;
            if (gp < CAP)
                ebuf[(size_t)b * CAP + gp] = ((unsigned long long)d << 32) | (unsigned)src[e];
        }
    }
}

__global__ void k_bscan(const int* __restrict__ bcnt, int NB, int* __restrict__ bbase) {
    __shared__ int sm[256];
    const int tid = threadIdx.x;
    const int c = (NB + 255) / 256;
    int s = 0;
    for (int k = 0; k < c; k++) { int i = tid * c + k; if (i < NB) s += bcnt[i]; }
    sm[tid] = s;
    __syncthreads();
    for (int off = 1; off < 256; off <<= 1) {
        int v = (tid >= off) ? sm[tid - off] : 0;
        __syncthreads();
        sm[tid] += v;
        __syncthreads();
    }
    int run = sm[tid] - s;
    for (int k = 0; k < c; k++) {
        int i = tid * c + k;
        if (i < NB) { bbase[i] = run; run += bcnt[i]; }
    }
}

__global__ __launch_bounds__(256) void k_binB(const unsigned long long* __restrict__ ebuf,
                                              int CAP, const int* __restrict__ bcnt,
                                              const int* __restrict__ bbase,
                                              int N, int E,
                                              int* __restrict__ rp, int* __restrict__ csr) {
    __shared__ int deg[256], sc[256], cur[256];
    const int tid = threadIdx.x;
    const int b = blockIdx.x;
    const int cnt = min(bcnt[b], CAP);
    const int cbase = bbase[b];
    deg[tid] = 0;
    __syncthreads();
    const unsigned long long* eb = ebuf + (size_t)b * CAP;
    for (int i = tid; i < cnt; i += 256) {
        int d = (int)(eb[i] >> 32);
        atomicAdd(&deg[d & 255], 1);
    }
    __syncthreads();
    int myDeg = deg[tid];
    sc[tid] = myDeg;
    __syncthreads();
    for (int off = 1; off < 256; off <<= 1) {
        int v = (tid >= off) ? sc[tid - off] : 0;
        __syncthreads();
        sc[tid] += v;
        __syncthreads();
    }
    int pos = cbase + sc[tid] - myDeg;
    int node = b * 256 + tid;
    if (node < N) rp[node] = pos;
    cur[tid] = pos;
    __syncthreads();
    for (int i = tid; i < cnt; i += 256) {
        unsigned long long e = eb[i];
        int d = (int)(e >> 32);
        int p = atomicAdd(&cur[d & 255], 1);
        csr[p] = (int)(e & 0xffffffffu);
    }
    if (b == 0 && tid == 0) rp[N] = E;
}

// ---------------- conversions / weight packing ----------------

__global__ void k_cvt_bf16(const float* __restrict__ in, uint4* __restrict__ out, int n8) {
    int i = blockIdx.x * 256 + threadIdx.x;
    if (i >= n8) return;
    const float4* p = reinterpret_cast<const float4*>(in) + (size_t)i * 2;
    float4 a = p[0], b = p[1];
    uint4 o;
    o.x = pk2(a.x, a.y); o.y = pk2(a.z, a.w);
    o.z = pk2(b.x, b.y); o.w = pk2(b.z, b.w);
    out[i] = o;
}

// pack one 128x128 f32 W into MFMA A-operand (W^T) fragment layout, split into
// bf16 hi plane (+0) and bf16 lo-residual plane (+16384)
__global__ void k_pack_w(const float* __restrict__ W, unsigned short* __restrict__ out) {
    int idx = blockIdx.x * 256 + threadIdx.x;  // 16384
    int k = idx >> 7, d = idx & 127;
    float w = W[idx];
    unsigned short h = f2bf(w);
    float hf = __uint_as_float((unsigned)h << 16);
    unsigned short l = f2bf(w - hf);
    int o = (((k >> 3) * 128) + d) * 8 + (k & 7);
    out[o] = h;
    out[16384 + o] = l;
}

// h table: out[n][d] = bf16(a[d]*y[n][d] + c[d]), y row stride 384
__global__ void k_cvt_h(const float* __restrict__ y,
                        const float* __restrict__ sa, const float* __restrict__ sc,
                        uint4* __restrict__ out, int N) {
    int idx = blockIdx.x * 256 + threadIdx.x;
    if (idx >= N * 16) return;
    int n = idx >> 4, cc = idx & 15;
    const float* p = y + (size_t)n * 384 + cc * 8;
    float4 x0 = *reinterpret_cast<const float4*>(p);
    float4 x1 = *reinterpret_cast<const float4*>(p + 4);
    const float4 a0 = *reinterpret_cast<const float4*>(sa + cc * 8);
    const float4 a1 = *reinterpret_cast<const float4*>(sa + cc * 8 + 4);
    const float4 c0 = *reinterpret_cast<const float4*>(sc + cc * 8);
    const float4 c1 = *reinterpret_cast<const float4*>(sc + cc * 8 + 4);
    uint4 o;
    o.x = pk2(fmaf(x0.x, a0.x, c0.x), fmaf(x0.y, a0.y, c0.y));
    o.y = pk2(fmaf(x0.z, a0.z, c0.z), fmaf(x0.w, a0.w, c0.w));
    o.z = pk2(fmaf(x1.x, a1.x, c1.x), fmaf(x1.y, a1.y, c1.y));
    o.w = pk2(fmaf(x1.z, a1.z, c1.z), fmaf(x1.w, a1.w, c1.w));
    out[(size_t)n * 16 + cc] = o;
}

// ---------------- aggregation (bf16 src rows, 16 lanes x 16B per node) -----

template <bool SELF, bool MEAN>
__global__ void k_aggr(const int* __restrict__ rp, const int* __restrict__ csr,
                       const uint4* __restrict__ src, uint4* __restrict__ out, int N) {
    int node = blockIdx.x * 16 + (threadIdx.x >> 4);
    if (node >= N) return;
    int c = threadIdx.x & 15;
    float acc[8];
    if (SELF) {
        unpack8(src[(size_t)node * 16 + c], acc);
    } else {
#pragma unroll
        for (int k = 0; k < 8; k++) acc[k] = 0.f;
    }
    int lo = rp[node], hi = rp[node + 1];
    for (int j = lo; j < hi; j++) {
        int sn = csr[j];
        float v[8];
        unpack8(src[(size_t)sn * 16 + c], v);
#pragma unroll
        for (int k = 0; k < 8; k++) acc[k] += v[k];
    }
    if (MEAN) {
        float inv = 1.0f / fmaxf((float)(hi - lo), 1.0f);
#pragma unroll
        for (int k = 0; k < 8; k++) acc[k] *= inv;
    }
    uint4 o;
    o.x = pk2(acc[0], acc[1]); o.y = pk2(acc[2], acc[3]);
    o.z = pk2(acc[4], acc[5]); o.w = pk2(acc[6], acc[7]);
    out[(size_t)node * 16 + c] = o;
}

// ---------------- MFMA helpers ----------------
// Swapped operands: mfma(A_op = W^T frag, B_op = node frag) -> C^T frags,
// lane holds node = l16, d = df*16 + lg*4 + reg. W streamed from L2, no LDS.

#define MFMA_STAGE(Whi, Wlo, B0, B1, ACC)                                          \
    _Pragma("unroll")                                                              \
    for (int ks = 0; ks < 4; ks++) {                                               \
        s8v b0 = __builtin_bit_cast(s8v, B0[ks]);                                  \
        s8v b1 = __builtin_bit_cast(s8v, B1[ks]);                                  \
        _Pragma("unroll")                                                          \
        for (int df = 0; df < 8; df++) {                                           \
            int wi = (ks * 4 + lg) * 128 + df * 16 + l16;                          \
            s8v ah = __builtin_bit_cast(s8v, Whi[wi]);                             \
            s8v al = __builtin_bit_cast(s8v, Wlo[wi]);                             \
            ACC[0][df] = __builtin_amdgcn_mfma_f32_16x16x32_bf16(ah, b0, ACC[0][df], 0, 0, 0); \
            ACC[1][df] = __builtin_amdgcn_mfma_f32_16x16x32_bf16(ah, b1, ACC[1][df], 0, 0, 0); \
            ACC[0][df] = __builtin_amdgcn_mfma_f32_16x16x32_bf16(al, b0, ACC[0][df], 0, 0, 0); \
            ACC[1][df] = __builtin_amdgcn_mfma_f32_16x16x32_bf16(al, b1, ACC[1][df], 0, 0, 0); \
        }                                                                          \
    }

// stats: per-channel sum/sumsq -> shfl over 16 node-lanes -> LDS -> atomics
#define STATS_EPILOGUE(OO, V0, V1)                                                 \
    {                                                                              \
        _Pragma("unroll")                                                          \
        for (int df = 0; df < 8; df++) {                                           \
            float s[4], q[4];                                                      \
            _Pragma("unroll")                                                      \
            for (int r = 0; r < 4; r++) {                                          \
                float a0 = V0 ? (&OO[0][df].x)[r] : 0.f;                           \
                float a1 = V1 ? (&OO[1][df].x)[r] : 0.f;                           \
                s[r] = a0 + a1;                                                    \
                q[r] = a0 * a0 + a1 * a1;                                          \
            }                                                                      \
            _Pragma("unroll")                                                      \
            for (int m = 1; m < 16; m <<= 1) {                                     \
                _Pragma("unroll")                                                  \
                for (int r = 0; r < 4; r++) {                                      \
                    s[r] += __shfl_xor(s[r], m, 64);                               \
                    q[r] += __shfl_xor(q[r], m, 64);                               \
                }                                                                  \
            }                                                                      \
            if (l16 == 0) {                                                        \
                _Pragma("unroll")                                                  \
                for (int r = 0; r < 4; r++) {                                      \
                    sred[wid][df * 16 + lg * 4 + r][0] = s[r];                     \
                    sred[wid][df * 16 + lg * 4 + r][1] = q[r];                     \
                }                                                                  \
            }                                                                      \
        }                                                                          \
        __syncthreads();                                                           \
        if (tid < 128) {                                                           \
            float s = sred[0][tid][0] + sred[1][tid][0] + sred[2][tid][0] + sred[3][tid][0]; \
            float q = sred[0][tid][1] + sred[1][tid][1] + sred[2][tid][1] + sred[3][tid][1]; \
            unsafeAtomicAdd(&gsum[tid], s);                                        \
            unsafeAtomicAdd(&gsq[tid], q);                                         \
        }                                                                          \
    }

// ---------------- SAGE GEMM: y0 = relu(A1@Wl + A2@Wr + b), f32 out + stats --

__global__ __launch_bounds__(256) void k_gemm_sage(
    const uint4* __restrict__ A1, const uint4* __restrict__ A2,
    const uint4* __restrict__ Wfrag,  // 2 terms x (hi,lo) x 2048 uint4
    const float* __restrict__ bias,
    float* __restrict__ outF, float* __restrict__ gsum, float* __restrict__ gsq,
    int N) {
    __shared__ float sred[4][128][2];
    const int tid = threadIdx.x;
    const int lane = tid & 63, wid = tid >> 6;
    const int nbase = blockIdx.x * 128 + wid * 32;
    const int l16 = lane & 15, lg = lane >> 4;

    f4v acc[2][8];
#pragma unroll
    for (int nf = 0; nf < 2; nf++)
#pragma unroll
        for (int df = 0; df < 8; df++)
            acc[nf][df] = (f4v){0.f, 0.f, 0.f, 0.f};

#pragma unroll
    for (int t = 0; t < 2; t++) {
        const uint4* A = t ? A2 : A1;
        const uint4* Whi = Wfrag + (size_t)t * 4096;
        const uint4* Wlo = Whi + 2048;
        uint4 bvec[2][4];
#pragma unroll
        for (int nf = 0; nf < 2; nf++) {
            const uint4* row = A + (size_t)(nbase + nf * 16 + l16) * 16;
#pragma unroll
            for (int ks = 0; ks < 4; ks++) bvec[nf][ks] = row[ks * 4 + lg];
        }
        MFMA_STAGE(Whi, Wlo, bvec[0], bvec[1], acc)
    }

    const bool v0 = (nbase + l16) < N;
    const bool v1 = (nbase + 16 + l16) < N;
    float4 oo[2][8];
#pragma unroll
    for (int df = 0; df < 8; df++) {
        int d0 = df * 16 + lg * 4;
        const float4 bb = *reinterpret_cast<const float4*>(bias + d0);
#pragma unroll
        for (int nf = 0; nf < 2; nf++) {
            oo[nf][df].x = fmaxf(acc[nf][df][0] + bb.x, 0.f);
            oo[nf][df].y = fmaxf(acc[nf][df][1] + bb.y, 0.f);
            oo[nf][df].z = fmaxf(acc[nf][df][2] + bb.z, 0.f);
            oo[nf][df].w = fmaxf(acc[nf][df][3] + bb.w, 0.f);
        }
    }

    STATS_EPILOGUE(oo, v0, v1)

#pragma unroll
    for (int nf = 0; nf < 2; nf++) {
        int n = nbase + nf * 16 + l16;
        if (n < N) {
#pragma unroll
            for (int df = 0; df < 8; df++)
                *reinterpret_cast<float4*>(outF + (size_t)n * 384 + df * 16 + lg * 4) = oo[nf][df];
        }
    }
}

// ---------------- fused GIN MLP: u = relu(relu(A@W1+b1)@W2+b2) --------------
// t tile staged in LDS (bf16, uint4-slot XOR swizzle col4 ^= row&15).

__global__ __launch_bounds__(256) void k_gemm_gin(
    const uint4* __restrict__ A,
    const uint4* __restrict__ W1f, const uint4* __restrict__ W2f,
    const float* __restrict__ b1, const float* __restrict__ b2,
    float* __restrict__ outF, float* __restrict__ gsum, float* __restrict__ gsq,
    int N) {
    __shared__ uint4 tile[2048];        // 32 KB t tile
    __shared__ float sred[4][128][2];
    const int tid = threadIdx.x;
    const int lane = tid & 63, wid = tid >> 6;
    const int nbase = blockIdx.x * 128 + wid * 32;
    const int l16 = lane & 15, lg = lane >> 4;

    f4v acc[2][8];
#pragma unroll
    for (int nf = 0; nf < 2; nf++)
#pragma unroll
        for (int df = 0; df < 8; df++)
            acc[nf][df] = (f4v){0.f, 0.f, 0.f, 0.f};

    // ---- stage 1: t = relu(A@W1 + b1) -> LDS (bf16) ----
    {
        const uint4* Whi = W1f;
        const uint4* Wlo = W1f + 2048;
        uint4 bvec[2][4];
#pragma unroll
        for (int nf = 0; nf < 2; nf++) {
            const uint4* row = A + (size_t)(nbase + nf * 16 + l16) * 16;
#pragma unroll
            for (int ks = 0; ks < 4; ks++) bvec[nf][ks] = row[ks * 4 + lg];
        }
        MFMA_STAGE(Whi, Wlo, bvec[0], bvec[1], acc)
    }
#pragma unroll
    for (int df = 0; df < 8; df++) {
        int d0 = df * 16 + lg * 4;
        const float4 bb = *reinterpret_cast<const float4*>(b1 + d0);
#pragma unroll
        for (int nf = 0; nf < 2; nf++) {
            float tx = fmaxf(acc[nf][df][0] + bb.x, 0.f);
            float ty = fmaxf(acc[nf][df][1] + bb.y, 0.f);
            float tz = fmaxf(acc[nf][df][2] + bb.z, 0.f);
            float tw = fmaxf(acc[nf][df][3] + bb.w, 0.f);
            uint2 p;
            p.x = pk2(tx, ty);
            p.y = pk2(tz, tw);
            int row = wid * 32 + nf * 16 + l16;           // local row 0..127
            int col4 = df * 2 + (lg >> 1);                // uint4 slot 0..15
            int slot = row * 16 + (col4 ^ (row & 15));
            *reinterpret_cast<uint2*>(
                reinterpret_cast<char*>(tile) + (size_t)slot * 16 + (lg & 1) * 8) = p;
        }
    }
    __syncthreads();

    // ---- stage 2: u = relu(t@W2 + b2) ----
#pragma unroll
    for (int nf = 0; nf < 2; nf++)
#pragma unroll
        for (int df = 0; df < 8; df++)
            acc[nf][df] = (f4v){0.f, 0.f, 0.f, 0.f};
    {
        const uint4* Whi = W2f;
        const uint4* Wlo = W2f + 2048;
        uint4 bvec[2][4];
#pragma unroll
        for (int nf = 0; nf < 2; nf++) {
            int row = wid * 32 + nf * 16 + l16;
#pragma unroll
            for (int ks = 0; ks < 4; ks++)
                bvec[nf][ks] = tile[row * 16 + ((ks * 4 + lg) ^ (row & 15))];
        }
        MFMA_STAGE(Whi, Wlo, bvec[0], bvec[1], acc)
    }

    const bool v0 = (nbase + l16) < N;
    const bool v1 = (nbase + 16 + l16) < N;
    float4 oo[2][8];
#pragma unroll
    for (int df = 0; df < 8; df++) {
        int d0 = df * 16 + lg * 4;
        const float4 bb = *reinterpret_cast<const float4*>(b2 + d0);
#pragma unroll
        for (int nf = 0; nf < 2; nf++) {
            oo[nf][df].x = fmaxf(acc[nf][df][0] + bb.x, 0.f);
            oo[nf][df].y = fmaxf(acc[nf][df][1] + bb.y, 0.f);
            oo[nf][df].z = fmaxf(acc[nf][df][2] + bb.z, 0.f);
            oo[nf][df].w = fmaxf(acc[nf][df][3] + bb.w, 0.f);
        }
    }

    STATS_EPILOGUE(oo, v0, v1)

#pragma unroll
    for (int nf = 0; nf < 2; nf++) {
        int n = nbase + nf * 16 + l16;
        if (n < N) {
#pragma unroll
            for (int df = 0; df < 8; df++)
                *reinterpret_cast<float4*>(outF + (size_t)n * 384 + df * 16 + lg * 4) = oo[nf][df];
        }
    }
}

// ---------------- BatchNorm finalize (also re-zeros accumulators) ----------

__global__ void k_bnfin(float* __restrict__ gsum, float* __restrict__ gsq,
                        const float* __restrict__ gamma, const float* __restrict__ beta,
                        int N, float* __restrict__ a, float* __restrict__ c) {
    int d = threadIdx.x;  // 128
    float invN = 1.0f / (float)N;
    float mu = gsum[d] * invN;
    float var = gsq[d] * invN - mu * mu;
    float rs = rsqrtf(var + BN_EPS);
    float aa = gamma[d] * rs;
    a[d] = aa;
    c[d] = beta[d] - mu * aa;
    gsum[d] = 0.f;   // ready for next layer's fused stats
    gsq[d] = 0.f;
}

// ---------------- fused normalize (in place) + add-pool --------------------

__global__ __launch_bounds__(384) void k_finpool(float* __restrict__ nf,
                                                 const float* __restrict__ a3,
                                                 const float* __restrict__ c3,
                                                 const int* __restrict__ batch,
                                                 int N, float* __restrict__ pooled) {
    const int d = threadIdx.x;  // 384
    const float a = a3[d], c = c3[d];
    const int n0 = blockIdx.x * 64;
    const int n1 = min(n0 + 64, N);
    float s = 0.f;
    int curg = batch[n0];
    for (int n = n0; n < n1; n++) {
        int g = batch[n];
        if (g != curg) {
            unsafeAtomicAdd(&pooled[(size_t)curg * 384 + d], s);
            s = 0.f;
            curg = g;
        }
        float v = nf[(size_t)n * 384 + d];
        float h = fmaf(v, a, c);
        nf[(size_t)n * 384 + d] = h;
        s += h;
    }
    unsafeAtomicAdd(&pooled[(size_t)curg * 384 + d], s);
}

// ---------------- launch ----------------

extern "C" void kernel_launch(void* const* d_in, const int* in_sizes, int n_in,
                              void* d_out, int out_size, void* d_ws, size_t ws_size,
                              hipStream_t stream) {
    const float* x   = (const float*)d_in[0];
    const int*   ei  = (const int*)d_in[1];
    const int*   bat = (const int*)d_in[2];
    const float* sWl = (const float*)d_in[3];
    const float* sbl = (const float*)d_in[4];
    const float* sWr = (const float*)d_in[5];
    const float* gW1 = (const float*)d_in[6];
    const float* gb1 = (const float*)d_in[7];
    const float* gW2 = (const float*)d_in[8];
    const float* gb2 = (const float*)d_in[9];
    const float* bng = (const float*)d_in[10];
    const float* bnb = (const float*)d_in[11];

    const int N = in_sizes[0] / 128;
    const int E = in_sizes[1] / 2;
    const int G = out_size / 384 - N;
    const int* srcp = ei;
    const int* dstp = ei + E;

    char* w = (char*)d_ws;
    auto alloc = [&](size_t bytes) -> void* {
        void* p = (void*)w;
        w += (bytes + 255) & ~(size_t)255;
        return p;
    };
    const size_t Npad = (size_t)(N + 128);
    int*   rp    = (int*)alloc(((size_t)N + 1) * 4);
    int*   csr   = (int*)alloc((size_t)E * 4);
    int*   bcnt  = (int*)alloc(8192);
    int*   bbase = (int*)alloc(8192);
    float* gsum  = (float*)alloc(512);
    float* gsq   = (float*)alloc(512);      // contiguous with gsum
    float* abuf  = (float*)alloc(3 * 512);  // a for layers 0..2
    float* cbuf  = (float*)alloc(3 * 512);  // c for layers 0..2
    // 6 weights x (hi+lo) x 16384 bf16: sWl, sWr, W1[0], W2[0], W1[1], W2[1]
    unsigned short* Wp = (unsigned short*)alloc((size_t)6 * 2 * 16384 * 2);
    unsigned short* ab = (unsigned short*)alloc(Npad * 256);  // aggregates / ebuf
    unsigned short* tb = (unsigned short*)alloc(Npad * 256);  // x / h tables

    float* pooled = (float*)d_out;                 // [G][384]
    float* nf     = pooled + (size_t)G * 384;      // [N][384]

    // bucket geometry (bucket = dst >> 8)
    const int NB  = (N + 255) / 256;
    int CAP = ((2 * (E / (NB > 0 ? NB : 1)) + 511) / 512) * 512;
    const long long maxcap = (long long)(Npad * 256) / ((long long)NB * 8);
    if ((long long)CAP > maxcap) CAP = (int)(maxcap & ~511LL);
    unsigned long long* ebuf = (unsigned long long*)ab;  // aliases ab

    const int egrid = (E + EPB - 1) / EPB;
    const int agrid = (N + 15) / 16;
    const int ggrid = (N + 127) / 128;
    const int vgrid = (N * 16 + 255) / 256;
    const int fgrid = (N + 63) / 64;

    // ---- CSR build (binned) ----
    hipMemsetAsync(bcnt, 0, (size_t)NB * 4, stream);
    k_binA<<<egrid, 256, 0, stream>>>(srcp, dstp, E, NB, CAP, bcnt, ebuf);
    k_bscan<<<1, 256, 0, stream>>>(bcnt, NB, bbase);
    k_binB<<<NB, 256, 0, stream>>>(ebuf, CAP, bcnt, bbase, N, E, rp, csr);

    // ---- prep: x -> bf16 (tb), weight packs, zero accum + pooled ----
    k_cvt_bf16<<<vgrid, 256, 0, stream>>>(x, (uint4*)tb, N * 16);
    k_pack_w<<<64, 256, 0, stream>>>(sWl,         Wp + 0 * 32768);
    k_pack_w<<<64, 256, 0, stream>>>(sWr,         Wp + 1 * 32768);
    k_pack_w<<<64, 256, 0, stream>>>(gW1,         Wp + 2 * 32768);
    k_pack_w<<<64, 256, 0, stream>>>(gW2,         Wp + 3 * 32768);
    k_pack_w<<<64, 256, 0, stream>>>(gW1 + 16384, Wp + 4 * 32768);
    k_pack_w<<<64, 256, 0, stream>>>(gW2 + 16384, Wp + 5 * 32768);
    hipMemsetAsync(gsum, 0, 1024, stream);
    hipMemsetAsync(pooled, 0, (size_t)G * 384 * 4, stream);

    // ---- Layer 0: SAGE ----
    k_aggr<false, true><<<agrid, 256, 0, stream>>>(rp, csr, (const uint4*)tb, (uint4*)ab, N);
    k_gemm_sage<<<ggrid, 256, 0, stream>>>(
        (const uint4*)ab, (const uint4*)tb, (const uint4*)Wp, sbl, nf, gsum, gsq, N);
    k_bnfin<<<1, 128, 0, stream>>>(gsum, gsq, bng, bnb, N, abuf, cbuf);
    // h0 table (bf16, rounded AFTER normalization) -> tb
    k_cvt_h<<<vgrid, 256, 0, stream>>>(nf, abuf, cbuf, (uint4*)tb, N);

    // ---- Layers 1,2: GIN ----
    for (int l = 1; l < 3; l++) {
        const uint4* W1p = (const uint4*)(Wp + (size_t)(2 * l) * 32768);      // slots 2,4
        const uint4* W2p = (const uint4*)(Wp + (size_t)(2 * l + 1) * 32768);  // slots 3,5
        const float* b1 = gb1 + (size_t)(l - 1) * 128;
        const float* b2 = gb2 + (size_t)(l - 1) * 128;
        float* nfl = nf + (size_t)l * 128;

        // ab = h + sum_nb h  (gather from tb)
        k_aggr<true, false><<<agrid, 256, 0, stream>>>(rp, csr, (const uint4*)tb, (uint4*)ab, N);
        // u = relu(relu(ab@W1+b1)@W2+b2) -> nf_l (f32) + stats (t staged in LDS)
        k_gemm_gin<<<ggrid, 256, 0, stream>>>(
            (const uint4*)ab, W1p, W2p, b1, b2, nfl, gsum, gsq, N);
        k_bnfin<<<1, 128, 0, stream>>>(gsum, gsq, bng + l * 128, bnb + l * 128, N,
                                       abuf + (size_t)l * 128, cbuf + (size_t)l * 128);
        // h_l table for next gather (only layer 1 needs it)
        if (l < 2)
            k_cvt_h<<<vgrid, 256, 0, stream>>>(nfl, abuf + (size_t)l * 128,
                                               cbuf + (size_t)l * 128, (uint4*)tb, N);
    }

    // ---- fused normalize + pool ----
    k_finpool<<<fgrid, 384, 0, stream>>>(nf, abuf, cbuf, bat, N, pooled);
}

// Round 9
// 591.307 us; speedup vs baseline: 1.8620x; 1.0501x over previous
//
#include <hip/hip_runtime.h>
#include <hip/hip_bf16.h>

// ---------------------------------------------------------------------------
// GNN encoder: SAGEConv -> BN -> 2x (GINConv -> BN), concat outputs + add-pool
// N=100000, E=1600000, F=D=128, L=3, G=500
// Round 9: wave-per-node gather (uniform trip count, 4 lane-groups x unroll 2
// = 8 row-loads in flight, cross-group shfl reduce) — attacks the
// latency-bound aggregation that dominates the profile. Rest = round 8.
// ---------------------------------------------------------------------------

#define BN_EPS 1e-5f
#define EPB 4096   // edges per block in bin pass A

typedef short s8v __attribute__((ext_vector_type(8)));
typedef float f4v __attribute__((ext_vector_type(4)));

__device__ __forceinline__ float bflo(unsigned u) { return __uint_as_float(u << 16); }
__device__ __forceinline__ float bfhi(unsigned u) { return __uint_as_float(u & 0xffff0000u); }
__device__ __forceinline__ unsigned short f2bf(float f) {
    unsigned u = __float_as_uint(f);
    unsigned r = (u + 0x7fffu + ((u >> 16) & 1u)) >> 16;  // RTNE
    return (unsigned short)r;
}
__device__ __forceinline__ unsigned pk2(float a, float b) {
    return (unsigned)f2bf(a) | ((unsigned)f2bf(b) << 16);
}
__device__ __forceinline__ void unpack8(uint4 u, float* v) {
    v[0] = bflo(u.x); v[1] = bfhi(u.x);
    v[2] = bflo(u.y); v[3] = bfhi(u.y);
    v[4] = bflo(u.z); v[5] = bfhi(u.z);
    v[6] = bflo(u.w); v[7] = bfhi(u.w);
}

// ---------------- CSR build (binned, 2-pass) ----------------

__global__ __launch_bounds__(256) void k_binA(const int* __restrict__ src,
                                              const int* __restrict__ dst, int E, int NB, int CAP,
                                              int* __restrict__ bcnt,
                                              unsigned long long* __restrict__ ebuf) {
    __shared__ int hist[512], base[512], cur[512];
    const int tid = threadIdx.x;
    const int e0 = blockIdx.x * EPB;
    for (int i = tid; i < 512; i += 256) { hist[i] = 0; cur[i] = 0; }
    __syncthreads();
#pragma unroll
    for (int k = 0; k < EPB / 256; k++) {
        int e = e0 + k * 256 + tid;
        if (e < E) atomicAdd(&hist[dst[e] >> 8], 1);
    }
    __syncthreads();
    for (int b = tid; b < NB; b += 256)
        base[b] = hist[b] ? atomicAdd(&bcnt[b], hist[b]) : 0;
    __syncthreads();
#pragma unroll
    for (int k = 0; k < EPB / 256; k++) {
        int e = e0 + k * 256 + tid;
        if (e < E) {
            int d = dst[e];
            int b = d >> 8;
            int lp = atomicAdd(&cur[b], 1);
            int gp = base[b] + lp;
            if (gp < CAP)
                ebuf[(size_t)b * CAP + gp] = ((unsigned long long)d << 32) | (unsigned)src[e];
        }
    }
}

__global__ void k_bscan(const int* __restrict__ bcnt, int NB, int* __restrict__ bbase) {
    __shared__ int sm[256];
    const int tid = threadIdx.x;
    const int c = (NB + 255) / 256;
    int s = 0;
    for (int k = 0; k < c; k++) { int i = tid * c + k; if (i < NB) s += bcnt[i]; }
    sm[tid] = s;
    __syncthreads();
    for (int off = 1; off < 256; off <<= 1) {
        int v = (tid >= off) ? sm[tid - off] : 0;
        __syncthreads();
        sm[tid] += v;
        __syncthreads();
    }
    int run = sm[tid] - s;
    for (int k = 0; k < c; k++) {
        int i = tid * c + k;
        if (i < NB) { bbase[i] = run; run += bcnt[i]; }
    }
}

__global__ __launch_bounds__(256) void k_binB(const unsigned long long* __restrict__ ebuf,
                                              int CAP, const int* __restrict__ bcnt,
                                              const int* __restrict__ bbase,
                                              int N, int E,
                                              int* __restrict__ rp, int* __restrict__ csr) {
    __shared__ int deg[256], sc[256], cur[256];
    const int tid = threadIdx.x;
    const int b = blockIdx.x;
    const int cnt = min(bcnt[b], CAP);
    const int cbase = bbase[b];
    deg[tid] = 0;
    __syncthreads();
    const unsigned long long* eb = ebuf + (size_t)b * CAP;
    for (int i = tid; i < cnt; i += 256) {
        int d = (int)(eb[i] >> 32);
        atomicAdd(&deg[d & 255], 1);
    }
    __syncthreads();
    int myDeg = deg[tid];
    sc[tid] = myDeg;
    __syncthreads();
    for (int off = 1; off < 256; off <<= 1) {
        int v = (tid >= off) ? sc[tid - off] : 0;
        __syncthreads();
        sc[tid] += v;
        __syncthreads();
    }
    int pos = cbase + sc[tid] - myDeg;
    int node = b * 256 + tid;
    if (node < N) rp[node] = pos;
    cur[tid] = pos;
    __syncthreads();
    for (int i = tid; i < cnt; i += 256) {
        unsigned long long e = eb[i];
        int d = (int)(e >> 32);
        int p = atomicAdd(&cur[d & 255], 1);
        csr[p] = (int)(e & 0xffffffffu);
    }
    if (b == 0 && tid == 0) rp[N] = E;
}

// ---------------- conversions / weight packing ----------------

__global__ void k_cvt_bf16(const float* __restrict__ in, uint4* __restrict__ out, int n8) {
    int i = blockIdx.x * 256 + threadIdx.x;
    if (i >= n8) return;
    const float4* p = reinterpret_cast<const float4*>(in) + (size_t)i * 2;
    float4 a = p[0], b = p[1];
    uint4 o;
    o.x = pk2(a.x, a.y); o.y = pk2(a.z, a.w);
    o.z = pk2(b.x, b.y); o.w = pk2(b.z, b.w);
    out[i] = o;
}

// pack one 128x128 f32 W into MFMA A-operand (W^T) fragment layout, split into
// bf16 hi plane (+0) and bf16 lo-residual plane (+16384)
__global__ void k_pack_w(const float* __restrict__ W, unsigned short* __restrict__ out) {
    int idx = blockIdx.x * 256 + threadIdx.x;  // 16384
    int k = idx >> 7, d = idx & 127;
    float w = W[idx];
    unsigned short h = f2bf(w);
    float hf = __uint_as_float((unsigned)h << 16);
    unsigned short l = f2bf(w - hf);
    int o = (((k >> 3) * 128) + d) * 8 + (k & 7);
    out[o] = h;
    out[16384 + o] = l;
}

// h table: out[n][d] = bf16(a[d]*y[n][d] + c[d]), y row stride 384
__global__ void k_cvt_h(const float* __restrict__ y,
                        const float* __restrict__ sa, const float* __restrict__ sc,
                        uint4* __restrict__ out, int N) {
    int idx = blockIdx.x * 256 + threadIdx.x;
    if (idx >= N * 16) return;
    int n = idx >> 4, cc = idx & 15;
    const float* p = y + (size_t)n * 384 + cc * 8;
    float4 x0 = *reinterpret_cast<const float4*>(p);
    float4 x1 = *reinterpret_cast<const float4*>(p + 4);
    const float4 a0 = *reinterpret_cast<const float4*>(sa + cc * 8);
    const float4 a1 = *reinterpret_cast<const float4*>(sa + cc * 8 + 4);
    const float4 c0 = *reinterpret_cast<const float4*>(sc + cc * 8);
    const float4 c1 = *reinterpret_cast<const float4*>(sc + cc * 8 + 4);
    uint4 o;
    o.x = pk2(fmaf(x0.x, a0.x, c0.x), fmaf(x0.y, a0.y, c0.y));
    o.y = pk2(fmaf(x0.z, a0.z, c0.z), fmaf(x0.w, a0.w, c0.w));
    o.z = pk2(fmaf(x1.x, a1.x, c1.x), fmaf(x1.y, a1.y, c1.y));
    o.w = pk2(fmaf(x1.z, a1.z, c1.z), fmaf(x1.w, a1.w, c1.w));
    out[(size_t)n * 16 + cc] = o;
}

// ---------------- aggregation: one node per WAVE ----------------
// 4 lane-groups of 16 lanes; group g handles neighbors j == g (mod 4),
// hand-unrolled x2 (two row loads in flight per lane); uniform trip count
// within the wave (no divergence); cross-group reduce via shfl_xor(16,32).

template <bool SELF, bool MEAN>
__global__ __launch_bounds__(256) void k_aggr(const int* __restrict__ rp,
                                              const int* __restrict__ csr,
                                              const uint4* __restrict__ src,
                                              uint4* __restrict__ out, int N) {
    const int node = blockIdx.x * 4 + (threadIdx.x >> 6);
    if (node >= N) return;
    const int lane = threadIdx.x & 63;
    const int c = lane & 15, grp = lane >> 4;

    float acc[8];
#pragma unroll
    for (int k = 0; k < 8; k++) acc[k] = 0.f;

    const int lo = rp[node], hi = rp[node + 1];
    int j = lo + grp;
    for (; j + 4 < hi; j += 8) {
        int sn0 = csr[j];
        int sn1 = csr[j + 4];
        uint4 r0 = src[(size_t)sn0 * 16 + c];
        uint4 r1 = src[(size_t)sn1 * 16 + c];
        float v[8];
        unpack8(r0, v);
#pragma unroll
        for (int k = 0; k < 8; k++) acc[k] += v[k];
        unpack8(r1, v);
#pragma unroll
        for (int k = 0; k < 8; k++) acc[k] += v[k];
    }
    if (j < hi) {
        float v[8];
        unpack8(src[(size_t)csr[j] * 16 + c], v);
#pragma unroll
        for (int k = 0; k < 8; k++) acc[k] += v[k];
    }

    // reduce the 4 group partials (lane bits 4 and 5)
#pragma unroll
    for (int k = 0; k < 8; k++) {
        acc[k] += __shfl_xor(acc[k], 16, 64);
        acc[k] += __shfl_xor(acc[k], 32, 64);
    }

    if (grp == 0) {
        if (SELF) {
            float v[8];
            unpack8(src[(size_t)node * 16 + c], v);
#pragma unroll
            for (int k = 0; k < 8; k++) acc[k] += v[k];
        }
        if (MEAN) {
            float inv = 1.0f / fmaxf((float)(hi - lo), 1.0f);
#pragma unroll
            for (int k = 0; k < 8; k++) acc[k] *= inv;
        }
        uint4 o;
        o.x = pk2(acc[0], acc[1]); o.y = pk2(acc[2], acc[3]);
        o.z = pk2(acc[4], acc[5]); o.w = pk2(acc[6], acc[7]);
        out[(size_t)node * 16 + c] = o;
    }
}

// ---------------- MFMA helpers ----------------
// Swapped operands: mfma(A_op = W^T frag, B_op = node frag) -> C^T frags,
// lane holds node = l16, d = df*16 + lg*4 + reg. W streamed from L2, no LDS.

#define MFMA_STAGE(Whi, Wlo, B0, B1, ACC)                                          \
    _Pragma("unroll")                                                              \
    for (int ks = 0; ks < 4; ks++) {                                               \
        s8v b0 = __builtin_bit_cast(s8v, B0[ks]);                                  \
        s8v b1 = __builtin_bit_cast(s8v, B1[ks]);                                  \
        _Pragma("unroll")                                                          \
        for (int df = 0; df < 8; df++) {                                           \
            int wi = (ks * 4 + lg) * 128 + df * 16 + l16;                          \
            s8v ah = __builtin_bit_cast(s8v, Whi[wi]);                             \
            s8v al = __builtin_bit_cast(s8v, Wlo[wi]);                             \
            ACC[0][df] = __builtin_amdgcn_mfma_f32_16x16x32_bf16(ah, b0, ACC[0][df], 0, 0, 0); \
            ACC[1][df] = __builtin_amdgcn_mfma_f32_16x16x32_bf16(ah, b1, ACC[1][df], 0, 0, 0); \
            ACC[0][df] = __builtin_amdgcn_mfma_f32_16x16x32_bf16(al, b0, ACC[0][df], 0, 0, 0); \
            ACC[1][df] = __builtin_amdgcn_mfma_f32_16x16x32_bf16(al, b1, ACC[1][df], 0, 0, 0); \
        }                                                                          \
    }

// stats: per-channel sum/sumsq -> shfl over 16 node-lanes -> LDS -> atomics
#define STATS_EPILOGUE(OO, V0, V1)                                                 \
    {                                                                              \
        _Pragma("unroll")                                                          \
        for (int df = 0; df < 8; df++) {                                           \
            float s[4], q[4];                                                      \
            _Pragma("unroll")                                                      \
            for (int r = 0; r < 4; r++) {                                          \
                float a0 = V0 ? (&OO[0][df].x)[r] : 0.f;                           \
                float a1 = V1 ? (&OO[1][df].x)[r] : 0.f;                           \
                s[r] = a0 + a1;                                                    \
                q[r] = a0 * a0 + a1 * a1;                                          \
            }                                                                      \
            _Pragma("unroll")                                                      \
            for (int m = 1; m < 16; m <<= 1) {                                     \
                _Pragma("unroll")                                                  \
                for (int r = 0; r < 4; r++) {                                      \
                    s[r] += __shfl_xor(s[r], m, 64);                               \
                    q[r] += __shfl_xor(q[r], m, 64);                               \
                }                                                                  \
            }                                                                      \
            if (l16 == 0) {                                                        \
                _Pragma("unroll")                                                  \
                for (int r = 0; r < 4; r++) {                                      \
                    sred[wid][df * 16 + lg * 4 + r][0] = s[r];                     \
                    sred[wid][df * 16 + lg * 4 + r][1] = q[r];                     \
                }                                                                  \
            }                                                                      \
        }                                                                          \
        __syncthreads();                                                           \
        if (tid < 128) {                                                           \
            float s = sred[0][tid][0] + sred[1][tid][0] + sred[2][tid][0] + sred[3][tid][0]; \
            float q = sred[0][tid][1] + sred[1][tid][1] + sred[2][tid][1] + sred[3][tid][1]; \
            unsafeAtomicAdd(&gsum[tid], s);                                        \
            unsafeAtomicAdd(&gsq[tid], q);                                         \
        }                                                                          \
    }

// ---------------- SAGE GEMM: y0 = relu(A1@Wl + A2@Wr + b), f32 out + stats --

__global__ __launch_bounds__(256) void k_gemm_sage(
    const uint4* __restrict__ A1, const uint4* __restrict__ A2,
    const uint4* __restrict__ Wfrag,  // 2 terms x (hi,lo) x 2048 uint4
    const float* __restrict__ bias,
    float* __restrict__ outF, float* __restrict__ gsum, float* __restrict__ gsq,
    int N) {
    __shared__ float sred[4][128][2];
    const int tid = threadIdx.x;
    const int lane = tid & 63, wid = tid >> 6;
    const int nbase = blockIdx.x * 128 + wid * 32;
    const int l16 = lane & 15, lg = lane >> 4;

    f4v acc[2][8];
#pragma unroll
    for (int nf = 0; nf < 2; nf++)
#pragma unroll
        for (int df = 0; df < 8; df++)
            acc[nf][df] = (f4v){0.f, 0.f, 0.f, 0.f};

#pragma unroll
    for (int t = 0; t < 2; t++) {
        const uint4* A = t ? A2 : A1;
        const uint4* Whi = Wfrag + (size_t)t * 4096;
        const uint4* Wlo = Whi + 2048;
        uint4 bvec[2][4];
#pragma unroll
        for (int nf = 0; nf < 2; nf++) {
            const uint4* row = A + (size_t)(nbase + nf * 16 + l16) * 16;
#pragma unroll
            for (int ks = 0; ks < 4; ks++) bvec[nf][ks] = row[ks * 4 + lg];
        }
        MFMA_STAGE(Whi, Wlo, bvec[0], bvec[1], acc)
    }

    const bool v0 = (nbase + l16) < N;
    const bool v1 = (nbase + 16 + l16) < N;
    float4 oo[2][8];
#pragma unroll
    for (int df = 0; df < 8; df++) {
        int d0 = df * 16 + lg * 4;
        const float4 bb = *reinterpret_cast<const float4*>(bias + d0);
#pragma unroll
        for (int nf = 0; nf < 2; nf++) {
            oo[nf][df].x = fmaxf(acc[nf][df][0] + bb.x, 0.f);
            oo[nf][df].y = fmaxf(acc[nf][df][1] + bb.y, 0.f);
            oo[nf][df].z = fmaxf(acc[nf][df][2] + bb.z, 0.f);
            oo[nf][df].w = fmaxf(acc[nf][df][3] + bb.w, 0.f);
        }
    }

    STATS_EPILOGUE(oo, v0, v1)

#pragma unroll
    for (int nf = 0; nf < 2; nf++) {
        int n = nbase + nf * 16 + l16;
        if (n < N) {
#pragma unroll
            for (int df = 0; df < 8; df++)
                *reinterpret_cast<float4*>(outF + (size_t)n * 384 + df * 16 + lg * 4) = oo[nf][df];
        }
    }
}

// ---------------- fused GIN MLP: u = relu(relu(A@W1+b1)@W2+b2) --------------
// t tile staged in LDS (bf16, uint4-slot XOR swizzle col4 ^= row&15).

__global__ __launch_bounds__(256) void k_gemm_gin(
    const uint4* __restrict__ A,
    const uint4* __restrict__ W1f, const uint4* __restrict__ W2f,
    const float* __restrict__ b1, const float* __restrict__ b2,
    float* __restrict__ outF, float* __restrict__ gsum, float* __restrict__ gsq,
    int N) {
    __shared__ uint4 tile[2048];        // 32 KB t tile
    __shared__ float sred[4][128][2];
    const int tid = threadIdx.x;
    const int lane = tid & 63, wid = tid >> 6;
    const int nbase = blockIdx.x * 128 + wid * 32;
    const int l16 = lane & 15, lg = lane >> 4;

    f4v acc[2][8];
#pragma unroll
    for (int nf = 0; nf < 2; nf++)
#pragma unroll
        for (int df = 0; df < 8; df++)
            acc[nf][df] = (f4v){0.f, 0.f, 0.f, 0.f};

    // ---- stage 1: t = relu(A@W1 + b1) -> LDS (bf16) ----
    {
        const uint4* Whi = W1f;
        const uint4* Wlo = W1f + 2048;
        uint4 bvec[2][4];
#pragma unroll
        for (int nf = 0; nf < 2; nf++) {
            const uint4* row = A + (size_t)(nbase + nf * 16 + l16) * 16;
#pragma unroll
            for (int ks = 0; ks < 4; ks++) bvec[nf][ks] = row[ks * 4 + lg];
        }
        MFMA_STAGE(Whi, Wlo, bvec[0], bvec[1], acc)
    }
#pragma unroll
    for (int df = 0; df < 8; df++) {
        int d0 = df * 16 + lg * 4;
        const float4 bb = *reinterpret_cast<const float4*>(b1 + d0);
#pragma unroll
        for (int nf = 0; nf < 2; nf++) {
            float tx = fmaxf(acc[nf][df][0] + bb.x, 0.f);
            float ty = fmaxf(acc[nf][df][1] + bb.y, 0.f);
            float tz = fmaxf(acc[nf][df][2] + bb.z, 0.f);
            float tw = fmaxf(acc[nf][df][3] + bb.w, 0.f);
            uint2 p;
            p.x = pk2(tx, ty);
            p.y = pk2(tz, tw);
            int row = wid * 32 + nf * 16 + l16;           // local row 0..127
            int col4 = df * 2 + (lg >> 1);                // uint4 slot 0..15
            int slot = row * 16 + (col4 ^ (row & 15));
            *reinterpret_cast<uint2*>(
                reinterpret_cast<char*>(tile) + (size_t)slot * 16 + (lg & 1) * 8) = p;
        }
    }
    __syncthreads();

    // ---- stage 2: u = relu(t@W2 + b2) ----
#pragma unroll
    for (int nf = 0; nf < 2; nf++)
#pragma unroll
        for (int df = 0; df < 8; df++)
            acc[nf][df] = (f4v){0.f, 0.f, 0.f, 0.f};
    {
        const uint4* Whi = W2f;
        const uint4* Wlo = W2f + 2048;
        uint4 bvec[2][4];
#pragma unroll
        for (int nf = 0; nf < 2; nf++) {
            int row = wid * 32 + nf * 16 + l16;
#pragma unroll
            for (int ks = 0; ks < 4; ks++)
                bvec[nf][ks] = tile[row * 16 + ((ks * 4 + lg) ^ (row & 15))];
        }
        MFMA_STAGE(Whi, Wlo, bvec[0], bvec[1], acc)
    }

    const bool v0 = (nbase + l16) < N;
    const bool v1 = (nbase + 16 + l16) < N;
    float4 oo[2][8];
#pragma unroll
    for (int df = 0; df < 8; df++) {
        int d0 = df * 16 + lg * 4;
        const float4 bb = *reinterpret_cast<const float4*>(b2 + d0);
#pragma unroll
        for (int nf = 0; nf < 2; nf++) {
            oo[nf][df].x = fmaxf(acc[nf][df][0] + bb.x, 0.f);
            oo[nf][df].y = fmaxf(acc[nf][df][1] + bb.y, 0.f);
            oo[nf][df].z = fmaxf(acc[nf][df][2] + bb.z, 0.f);
            oo[nf][df].w = fmaxf(acc[nf][df][3] + bb.w, 0.f);
        }
    }

    STATS_EPILOGUE(oo, v0, v1)

#pragma unroll
    for (int nf = 0; nf < 2; nf++) {
        int n = nbase + nf * 16 + l16;
        if (n < N) {
#pragma unroll
            for (int df = 0; df < 8; df++)
                *reinterpret_cast<float4*>(outF + (size_t)n * 384 + df * 16 + lg * 4) = oo[nf][df];
        }
    }
}

// ---------------- BatchNorm finalize (also re-zeros accumulators) ----------

__global__ void k_bnfin(float* __restrict__ gsum, float* __restrict__ gsq,
                        const float* __restrict__ gamma, const float* __restrict__ beta,
                        int N, float* __restrict__ a, float* __restrict__ c) {
    int d = threadIdx.x;  // 128
    float invN = 1.0f / (float)N;
    float mu = gsum[d] * invN;
    float var = gsq[d] * invN - mu * mu;
    float rs = rsqrtf(var + BN_EPS);
    float aa = gamma[d] * rs;
    a[d] = aa;
    c[d] = beta[d] - mu * aa;
    gsum[d] = 0.f;   // ready for next layer's fused stats
    gsq[d] = 0.f;
}

// ---------------- fused normalize (in place) + add-pool --------------------

__global__ __launch_bounds__(384) void k_finpool(float* __restrict__ nf,
                                                 const float* __restrict__ a3,
                                                 const float* __restrict__ c3,
                                                 const int* __restrict__ batch,
                                                 int N, float* __restrict__ pooled) {
    const int d = threadIdx.x;  // 384
    const float a = a3[d], c = c3[d];
    const int n0 = blockIdx.x * 64;
    const int n1 = min(n0 + 64, N);
    float s = 0.f;
    int curg = batch[n0];
    for (int n = n0; n < n1; n++) {
        int g = batch[n];
        if (g != curg) {
            unsafeAtomicAdd(&pooled[(size_t)curg * 384 + d], s);
            s = 0.f;
            curg = g;
        }
        float v = nf[(size_t)n * 384 + d];
        float h = fmaf(v, a, c);
        nf[(size_t)n * 384 + d] = h;
        s += h;
    }
    unsafeAtomicAdd(&pooled[(size_t)curg * 384 + d], s);
}

// ---------------- launch ----------------

extern "C" void kernel_launch(void* const* d_in, const int* in_sizes, int n_in,
                              void* d_out, int out_size, void* d_ws, size_t ws_size,
                              hipStream_t stream) {
    const float* x   = (const float*)d_in[0];
    const int*   ei  = (const int*)d_in[1];
    const int*   bat = (const int*)d_in[2];
    const float* sWl = (const float*)d_in[3];
    const float* sbl = (const float*)d_in[4];
    const float* sWr = (const float*)d_in[5];
    const float* gW1 = (const float*)d_in[6];
    const float* gb1 = (const float*)d_in[7];
    const float* gW2 = (const float*)d_in[8];
    const float* gb2 = (const float*)d_in[9];
    const float* bng = (const float*)d_in[10];
    const float* bnb = (const float*)d_in[11];

    const int N = in_sizes[0] / 128;
    const int E = in_sizes[1] / 2;
    const int G = out_size / 384 - N;
    const int* srcp = ei;
    const int* dstp = ei + E;

    char* w = (char*)d_ws;
    auto alloc = [&](size_t bytes) -> void* {
        void* p = (void*)w;
        w += (bytes + 255) & ~(size_t)255;
        return p;
    };
    const size_t Npad = (size_t)(N + 128);
    int*   rp    = (int*)alloc(((size_t)N + 1) * 4);
    int*   csr   = (int*)alloc((size_t)E * 4);
    int*   bcnt  = (int*)alloc(8192);
    int*   bbase = (int*)alloc(8192);
    float* gsum  = (float*)alloc(512);
    float* gsq   = (float*)alloc(512);      // contiguous with gsum
    float* abuf  = (float*)alloc(3 * 512);  // a for layers 0..2
    float* cbuf  = (float*)alloc(3 * 512);  // c for layers 0..2
    // 6 weights x (hi+lo) x 16384 bf16: sWl, sWr, W1[0], W2[0], W1[1], W2[1]
    unsigned short* Wp = (unsigned short*)alloc((size_t)6 * 2 * 16384 * 2);
    unsigned short* ab = (unsigned short*)alloc(Npad * 256);  // aggregates / ebuf
    unsigned short* tb = (unsigned short*)alloc(Npad * 256);  // x / h tables

    float* pooled = (float*)d_out;                 // [G][384]
    float* nf     = pooled + (size_t)G * 384;      // [N][384]

    // bucket geometry (bucket = dst >> 8)
    const int NB  = (N + 255) / 256;
    int CAP = ((2 * (E / (NB > 0 ? NB : 1)) + 511) / 512) * 512;
    const long long maxcap = (long long)(Npad * 256) / ((long long)NB * 8);
    if ((long long)CAP > maxcap) CAP = (int)(maxcap & ~511LL);
    unsigned long long* ebuf = (unsigned long long*)ab;  // aliases ab

    const int egrid = (E + EPB - 1) / EPB;
    const int agrid = (N + 3) / 4;
    const int ggrid = (N + 127) / 128;
    const int vgrid = (N * 16 + 255) / 256;
    const int fgrid = (N + 63) / 64;

    // ---- CSR build (binned) ----
    hipMemsetAsync(bcnt, 0, (size_t)NB * 4, stream);
    k_binA<<<egrid, 256, 0, stream>>>(srcp, dstp, E, NB, CAP, bcnt, ebuf);
    k_bscan<<<1, 256, 0, stream>>>(bcnt, NB, bbase);
    k_binB<<<NB, 256, 0, stream>>>(ebuf, CAP, bcnt, bbase, N, E, rp, csr);

    // ---- prep: x -> bf16 (tb), weight packs, zero accum + pooled ----
    k_cvt_bf16<<<vgrid, 256, 0, stream>>>(x, (uint4*)tb, N * 16);
    k_pack_w<<<64, 256, 0, stream>>>(sWl,         Wp + 0 * 32768);
    k_pack_w<<<64, 256, 0, stream>>>(sWr,         Wp + 1 * 32768);
    k_pack_w<<<64, 256, 0, stream>>>(gW1,         Wp + 2 * 32768);
    k_pack_w<<<64, 256, 0, stream>>>(gW2,         Wp + 3 * 32768);
    k_pack_w<<<64, 256, 0, stream>>>(gW1 + 16384, Wp + 4 * 32768);
    k_pack_w<<<64, 256, 0, stream>>>(gW2 + 16384, Wp + 5 * 32768);
    hipMemsetAsync(gsum, 0, 1024, stream);
    hipMemsetAsync(pooled, 0, (size_t)G * 384 * 4, stream);

    // ---- Layer 0: SAGE ----
    k_aggr<false, true><<<agrid, 256, 0, stream>>>(rp, csr, (const uint4*)tb, (uint4*)ab, N);
    k_gemm_sage<<<ggrid, 256, 0, stream>>>(
        (const uint4*)ab, (const uint4*)tb, (const uint4*)Wp, sbl, nf, gsum, gsq, N);
    k_bnfin<<<1, 128, 0, stream>>>(gsum, gsq, bng, bnb, N, abuf, cbuf);
    // h0 table (bf16, rounded AFTER normalization) -> tb
    k_cvt_h<<<vgrid, 256, 0, stream>>>(nf, abuf, cbuf, (uint4*)tb, N);

    // ---- Layers 1,2: GIN ----
    for (int l = 1; l < 3; l++) {
        const uint4* W1p = (const uint4*)(Wp + (size_t)(2 * l) * 32768);      // slots 2,4
        const uint4* W2p = (const uint4*)(Wp + (size_t)(2 * l + 1) * 32768);  // slots 3,5
        const float* b1 = gb1 + (size_t)(l - 1) * 128;
        const float* b2 = gb2 + (size_t)(l - 1) * 128;
        float* nfl = nf + (size_t)l * 128;

        // ab = h + sum_nb h  (gather from tb)
        k_aggr<true, false><<<agrid, 256, 0, stream>>>(rp, csr, (const uint4*)tb, (uint4*)ab, N);
        // u = relu(relu(ab@W1+b1)@W2+b2) -> nf_l (f32) + stats (t staged in LDS)
        k_gemm_gin<<<ggrid, 256, 0, stream>>>(
            (const uint4*)ab, W1p, W2p, b1, b2, nfl, gsum, gsq, N);
        k_bnfin<<<1, 128, 0, stream>>>(gsum, gsq, bng + l * 128, bnb + l * 128, N,
                                       abuf + (size_t)l * 128, cbuf + (size_t)l * 128);
        // h_l table for next gather (only layer 1 needs it)
        if (l < 2)
            k_cvt_h<<<vgrid, 256, 0, stream>>>(nfl, abuf + (size_t)l * 128,
                                               cbuf + (size_t)l * 128, (uint4*)tb, N);
    }

    // ---- fused normalize + pool ----
    k_finpool<<<fgrid, 384, 0, stream>>>(nf, abuf, cbuf, bat, N, pooled);
}

// Round 10
// 561.949 us; speedup vs baseline: 1.9593x; 1.0522x over previous
//
#include <hip/hip_runtime.h>
#include <hip/hip_bf16.h>

// ---------------------------------------------------------------------------
// GNN encoder: SAGEConv -> BN -> 2x (GINConv -> BN), concat outputs + add-pool
// N=100000, E=1600000, F=D=128, L=3, G=500
// Round 10: dispatch-count surgery — bscan folded into binB, bnfin eliminated
// (consumers recompute a,c from per-layer stats slots), packs fused into one
// kernel, single zero-memset; gather unrolled 4-deep (16 rows in flight).
// Numerics identical to round 8/9 (absmax 1.25).
// ---------------------------------------------------------------------------

#define BN_EPS 1e-5f
#define EPB 4096   // edges per block in bin pass A

typedef short s8v __attribute__((ext_vector_type(8)));
typedef float f4v __attribute__((ext_vector_type(4)));

__device__ __forceinline__ float bflo(unsigned u) { return __uint_as_float(u << 16); }
__device__ __forceinline__ float bfhi(unsigned u) { return __uint_as_float(u & 0xffff0000u); }
__device__ __forceinline__ unsigned short f2bf(float f) {
    unsigned u = __float_as_uint(f);
    unsigned r = (u + 0x7fffu + ((u >> 16) & 1u)) >> 16;  // RTNE
    return (unsigned short)r;
}
__device__ __forceinline__ unsigned pk2(float a, float b) {
    return (unsigned)f2bf(a) | ((unsigned)f2bf(b) << 16);
}
__device__ __forceinline__ void unpack8(uint4 u, float* v) {
    v[0] = bflo(u.x); v[1] = bfhi(u.x);
    v[2] = bflo(u.y); v[3] = bfhi(u.y);
    v[4] = bflo(u.z); v[5] = bfhi(u.z);
    v[6] = bflo(u.w); v[7] = bfhi(u.w);
}

// ---------------- CSR build (binned, 2-pass; scan folded into pass B) ------

__global__ __launch_bounds__(256) void k_binA(const int* __restrict__ src,
                                              const int* __restrict__ dst, int E, int NB, int CAP,
                                              int* __restrict__ bcnt,
                                              unsigned long long* __restrict__ ebuf) {
    __shared__ int hist[512], base[512], cur[512];
    const int tid = threadIdx.x;
    const int e0 = blockIdx.x * EPB;
    for (int i = tid; i < 512; i += 256) { hist[i] = 0; cur[i] = 0; }
    __syncthreads();
#pragma unroll
    for (int k = 0; k < EPB / 256; k++) {
        int e = e0 + k * 256 + tid;
        if (e < E) atomicAdd(&hist[dst[e] >> 8], 1);
    }
    __syncthreads();
    for (int b = tid; b < NB; b += 256)
        base[b] = hist[b] ? atomicAdd(&bcnt[b], hist[b]) : 0;
    __syncthreads();
#pragma unroll
    for (int k = 0; k < EPB / 256; k++) {
        int e = e0 + k * 256 + tid;
        if (e < E) {
            int d = dst[e];
            int b = d >> 8;
            int lp = atomicAdd(&cur[b], 1);
            int gp = base[b] + lp;
            if (gp < CAP)
                ebuf[(size_t)b * CAP + gp] = ((unsigned long long)d << 32) | (unsigned)src[e];
        }
    }
}

__global__ __launch_bounds__(256) void k_binB(const unsigned long long* __restrict__ ebuf,
                                              int CAP, const int* __restrict__ bcnt,
                                              int N, int E,
                                              int* __restrict__ rp, int* __restrict__ csr) {
    __shared__ int deg[256], sc[256], cur[256];
    __shared__ int s_cbase;
    const int tid = threadIdx.x;
    const int b = blockIdx.x;
    const int cnt = min(bcnt[b], CAP);

    // inline exclusive prefix over buckets: cbase = sum bcnt[0..b)
    int partial = 0;
    for (int i = tid; i < b; i += 256) partial += bcnt[i];
    sc[tid] = partial;
    __syncthreads();
    for (int off = 128; off > 0; off >>= 1) {
        if (tid < off) sc[tid] += sc[tid + off];
        __syncthreads();
    }
    if (tid == 0) s_cbase = sc[0];
    __syncthreads();
    const int cbase = s_cbase;

    deg[tid] = 0;
    __syncthreads();
    const unsigned long long* eb = ebuf + (size_t)b * CAP;
    for (int i = tid; i < cnt; i += 256) {
        int d = (int)(eb[i] >> 32);
        atomicAdd(&deg[d & 255], 1);
    }
    __syncthreads();
    int myDeg = deg[tid];
    sc[tid] = myDeg;
    __syncthreads();
    for (int off = 1; off < 256; off <<= 1) {
        int v = (tid >= off) ? sc[tid - off] : 0;
        __syncthreads();
        sc[tid] += v;
        __syncthreads();
    }
    int pos = cbase + sc[tid] - myDeg;
    int node = b * 256 + tid;
    if (node < N) rp[node] = pos;
    cur[tid] = pos;
    __syncthreads();
    for (int i = tid; i < cnt; i += 256) {
        unsigned long long e = eb[i];
        int d = (int)(e >> 32);
        int p = atomicAdd(&cur[d & 255], 1);
        csr[p] = (int)(e & 0xffffffffu);
    }
    if (b == 0 && tid == 0) rp[N] = E;
}

// ---------------- conversions / weight packing ----------------

__global__ void k_cvt_bf16(const float* __restrict__ in, uint4* __restrict__ out, int n8) {
    int i = blockIdx.x * 256 + threadIdx.x;
    if (i >= n8) return;
    const float4* p = reinterpret_cast<const float4*>(in) + (size_t)i * 2;
    float4 a = p[0], b = p[1];
    uint4 o;
    o.x = pk2(a.x, a.y); o.y = pk2(a.z, a.w);
    o.z = pk2(b.x, b.y); o.w = pk2(b.z, b.w);
    out[i] = o;
}

// pack all 6 128x128 f32 W into MFMA A-operand (W^T) fragment layout,
// hi plane (+0) / lo residual plane (+16384) per weight slot.
__global__ void k_pack_all(const float* __restrict__ sWl, const float* __restrict__ sWr,
                           const float* __restrict__ gW1, const float* __restrict__ gW2,
                           unsigned short* __restrict__ out) {
    int gid = blockIdx.x;           // 6 * 64 blocks
    int wsel = gid >> 6;
    int idx = (gid & 63) * 256 + threadIdx.x;  // 0..16383
    const float* W;
    switch (wsel) {
        case 0: W = sWl; break;
        case 1: W = sWr; break;
        case 2: W = gW1; break;
        case 3: W = gW2; break;
        case 4: W = gW1 + 16384; break;
        default: W = gW2 + 16384; break;
    }
    int k = idx >> 7, d = idx & 127;
    float w = W[idx];
    unsigned short h = f2bf(w);
    float hf = __uint_as_float((unsigned)h << 16);
    unsigned short l = f2bf(w - hf);
    int o = (((k >> 3) * 128) + d) * 8 + (k & 7);
    unsigned short* slot = out + (size_t)wsel * 32768;
    slot[o] = h;
    slot[16384 + o] = l;
}

// h table: out[n][d] = bf16(a[d]*y[n][d] + c[d]); a,c recomputed from raw
// per-layer BN stats (identical f32 math as the old k_bnfin).
__global__ void k_cvt_h(const float* __restrict__ y,
                        const float* __restrict__ gsumL, const float* __restrict__ gsqL,
                        const float* __restrict__ gamma, const float* __restrict__ beta,
                        float invN, uint4* __restrict__ out, int N) {
    int idx = blockIdx.x * 256 + threadIdx.x;
    if (idx >= N * 16) return;
    int n = idx >> 4, cc = idx & 15;
    float av[8], cv[8];
#pragma unroll
    for (int k = 0; k < 8; k++) {
        int d = cc * 8 + k;
        float mu = gsumL[d] * invN;
        float var = gsqL[d] * invN - mu * mu;
        float rs = rsqrtf(var + BN_EPS);
        float aa = gamma[d] * rs;
        av[k] = aa;
        cv[k] = beta[d] - mu * aa;
    }
    const float* p = y + (size_t)n * 384 + cc * 8;
    float4 x0 = *reinterpret_cast<const float4*>(p);
    float4 x1 = *reinterpret_cast<const float4*>(p + 4);
    uint4 o;
    o.x = pk2(fmaf(x0.x, av[0], cv[0]), fmaf(x0.y, av[1], cv[1]));
    o.y = pk2(fmaf(x0.z, av[2], cv[2]), fmaf(x0.w, av[3], cv[3]));
    o.z = pk2(fmaf(x1.x, av[4], cv[4]), fmaf(x1.y, av[5], cv[5]));
    o.w = pk2(fmaf(x1.z, av[6], cv[6]), fmaf(x1.w, av[7], cv[7]));
    out[(size_t)n * 16 + cc] = o;
}

// ---------------- aggregation: one node per WAVE ----------------
// 4 lane-groups of 16 lanes; group g handles neighbors j == g (mod 4),
// unrolled 4-deep (16 rows in flight per wave); uniform trip count within
// the wave; cross-group reduce via shfl_xor(16,32).

template <bool SELF, bool MEAN>
__global__ __launch_bounds__(256) void k_aggr(const int* __restrict__ rp,
                                              const int* __restrict__ csr,
                                              const uint4* __restrict__ src,
                                              uint4* __restrict__ out, int N) {
    const int node = blockIdx.x * 4 + (threadIdx.x >> 6);
    if (node >= N) return;
    const int lane = threadIdx.x & 63;
    const int c = lane & 15, grp = lane >> 4;

    float acc[8];
#pragma unroll
    for (int k = 0; k < 8; k++) acc[k] = 0.f;

    const int lo = rp[node], hi = rp[node + 1];
    int j = lo + grp;
    for (; j + 12 < hi; j += 16) {
        int sn0 = csr[j];
        int sn1 = csr[j + 4];
        int sn2 = csr[j + 8];
        int sn3 = csr[j + 12];
        uint4 r0 = src[(size_t)sn0 * 16 + c];
        uint4 r1 = src[(size_t)sn1 * 16 + c];
        uint4 r2 = src[(size_t)sn2 * 16 + c];
        uint4 r3 = src[(size_t)sn3 * 16 + c];
        float v[8];
        unpack8(r0, v);
#pragma unroll
        for (int k = 0; k < 8; k++) acc[k] += v[k];
        unpack8(r1, v);
#pragma unroll
        for (int k = 0; k < 8; k++) acc[k] += v[k];
        unpack8(r2, v);
#pragma unroll
        for (int k = 0; k < 8; k++) acc[k] += v[k];
        unpack8(r3, v);
#pragma unroll
        for (int k = 0; k < 8; k++) acc[k] += v[k];
    }
    for (; j + 4 < hi; j += 8) {
        int sn0 = csr[j];
        int sn1 = csr[j + 4];
        uint4 r0 = src[(size_t)sn0 * 16 + c];
        uint4 r1 = src[(size_t)sn1 * 16 + c];
        float v[8];
        unpack8(r0, v);
#pragma unroll
        for (int k = 0; k < 8; k++) acc[k] += v[k];
        unpack8(r1, v);
#pragma unroll
        for (int k = 0; k < 8; k++) acc[k] += v[k];
    }
    if (j < hi) {
        float v[8];
        unpack8(src[(size_t)csr[j] * 16 + c], v);
#pragma unroll
        for (int k = 0; k < 8; k++) acc[k] += v[k];
    }

#pragma unroll
    for (int k = 0; k < 8; k++) {
        acc[k] += __shfl_xor(acc[k], 16, 64);
        acc[k] += __shfl_xor(acc[k], 32, 64);
    }

    if (grp == 0) {
        if (SELF) {
            float v[8];
            unpack8(src[(size_t)node * 16 + c], v);
#pragma unroll
            for (int k = 0; k < 8; k++) acc[k] += v[k];
        }
        if (MEAN) {
            float inv = 1.0f / fmaxf((float)(hi - lo), 1.0f);
#pragma unroll
            for (int k = 0; k < 8; k++) acc[k] *= inv;
        }
        uint4 o;
        o.x = pk2(acc[0], acc[1]); o.y = pk2(acc[2], acc[3]);
        o.z = pk2(acc[4], acc[5]); o.w = pk2(acc[6], acc[7]);
        out[(size_t)node * 16 + c] = o;
    }
}

// ---------------- MFMA helpers ----------------
// Swapped operands: mfma(A_op = W^T frag, B_op = node frag) -> C^T frags,
// lane holds node = l16, d = df*16 + lg*4 + reg. W streamed from L2, no LDS.

#define MFMA_STAGE(Whi, Wlo, B0, B1, ACC)                                          \
    _Pragma("unroll")                                                              \
    for (int ks = 0; ks < 4; ks++) {                                               \
        s8v b0 = __builtin_bit_cast(s8v, B0[ks]);                                  \
        s8v b1 = __builtin_bit_cast(s8v, B1[ks]);                                  \
        _Pragma("unroll")                                                          \
        for (int df = 0; df < 8; df++) {                                           \
            int wi = (ks * 4 + lg) * 128 + df * 16 + l16;                          \
            s8v ah = __builtin_bit_cast(s8v, Whi[wi]);                             \
            s8v al = __builtin_bit_cast(s8v, Wlo[wi]);                             \
            ACC[0][df] = __builtin_amdgcn_mfma_f32_16x16x32_bf16(ah, b0, ACC[0][df], 0, 0, 0); \
            ACC[1][df] = __builtin_amdgcn_mfma_f32_16x16x32_bf16(ah, b1, ACC[1][df], 0, 0, 0); \
            ACC[0][df] = __builtin_amdgcn_mfma_f32_16x16x32_bf16(al, b0, ACC[0][df], 0, 0, 0); \
            ACC[1][df] = __builtin_amdgcn_mfma_f32_16x16x32_bf16(al, b1, ACC[1][df], 0, 0, 0); \
        }                                                                          \
    }

// stats: per-channel sum/sumsq -> shfl over 16 node-lanes -> LDS -> atomics
#define STATS_EPILOGUE(OO, V0, V1)                                                 \
    {                                                                              \
        _Pragma("unroll")                                                          \
        for (int df = 0; df < 8; df++) {                                           \
            float s[4], q[4];                                                      \
            _Pragma("unroll")                                                      \
            for (int r = 0; r < 4; r++) {                                          \
                float a0 = V0 ? (&OO[0][df].x)[r] : 0.f;                           \
                float a1 = V1 ? (&OO[1][df].x)[r] : 0.f;                           \
                s[r] = a0 + a1;                                                    \
                q[r] = a0 * a0 + a1 * a1;                                          \
            }                                                                      \
            _Pragma("unroll")                                                      \
            for (int m = 1; m < 16; m <<= 1) {                                     \
                _Pragma("unroll")                                                  \
                for (int r = 0; r < 4; r++) {                                      \
                    s[r] += __shfl_xor(s[r], m, 64);                               \
                    q[r] += __shfl_xor(q[r], m, 64);                               \
                }                                                                  \
            }                                                                      \
            if (l16 == 0) {                                                        \
                _Pragma("unroll")                                                  \
                for (int r = 0; r < 4; r++) {                                      \
                    sred[wid][df * 16 + lg * 4 + r][0] = s[r];                     \
                    sred[wid][df * 16 + lg * 4 + r][1] = q[r];                     \
                }                                                                  \
            }                                                                      \
        }                                                                          \
        __syncthreads();                                                           \
        if (tid < 128) {                                                           \
            float s = sred[0][tid][0] + sred[1][tid][0] + sred[2][tid][0] + sred[3][tid][0]; \
            float q = sred[0][tid][1] + sred[1][tid][1] + sred[2][tid][1] + sred[3][tid][1]; \
            unsafeAtomicAdd(&gsum[tid], s);                                        \
            unsafeAtomicAdd(&gsq[tid], q);                                         \
        }                                                                          \
    }

// ---------------- SAGE GEMM: y0 = relu(A1@Wl + A2@Wr + b), f32 out + stats --

__global__ __launch_bounds__(256) void k_gemm_sage(
    const uint4* __restrict__ A1, const uint4* __restrict__ A2,
    const uint4* __restrict__ Wfrag,  // 2 terms x (hi,lo) x 2048 uint4
    const float* __restrict__ bias,
    float* __restrict__ outF, float* __restrict__ gsum, float* __restrict__ gsq,
    int N) {
    __shared__ float sred[4][128][2];
    const int tid = threadIdx.x;
    const int lane = tid & 63, wid = tid >> 6;
    const int nbase = blockIdx.x * 128 + wid * 32;
    const int l16 = lane & 15, lg = lane >> 4;

    f4v acc[2][8];
#pragma unroll
    for (int nf = 0; nf < 2; nf++)
#pragma unroll
        for (int df = 0; df < 8; df++)
            acc[nf][df] = (f4v){0.f, 0.f, 0.f, 0.f};

#pragma unroll
    for (int t = 0; t < 2; t++) {
        const uint4* A = t ? A2 : A1;
        const uint4* Whi = Wfrag + (size_t)t * 4096;
        const uint4* Wlo = Whi + 2048;
        uint4 bvec[2][4];
#pragma unroll
        for (int nf = 0; nf < 2; nf++) {
            const uint4* row = A + (size_t)(nbase + nf * 16 + l16) * 16;
#pragma unroll
            for (int ks = 0; ks < 4; ks++) bvec[nf][ks] = row[ks * 4 + lg];
        }
        MFMA_STAGE(Whi, Wlo, bvec[0], bvec[1], acc)
    }

    const bool v0 = (nbase + l16) < N;
    const bool v1 = (nbase + 16 + l16) < N;
    float4 oo[2][8];
#pragma unroll
    for (int df = 0; df < 8; df++) {
        int d0 = df * 16 + lg * 4;
        const float4 bb = *reinterpret_cast<const float4*>(bias + d0);
#pragma unroll
        for (int nf = 0; nf < 2; nf++) {
            oo[nf][df].x = fmaxf(acc[nf][df][0] + bb.x, 0.f);
            oo[nf][df].y = fmaxf(acc[nf][df][1] + bb.y, 0.f);
            oo[nf][df].z = fmaxf(acc[nf][df][2] + bb.z, 0.f);
            oo[nf][df].w = fmaxf(acc[nf][df][3] + bb.w, 0.f);
        }
    }

    STATS_EPILOGUE(oo, v0, v1)

#pragma unroll
    for (int nf = 0; nf < 2; nf++) {
        int n = nbase + nf * 16 + l16;
        if (n < N) {
#pragma unroll
            for (int df = 0; df < 8; df++)
                *reinterpret_cast<float4*>(outF + (size_t)n * 384 + df * 16 + lg * 4) = oo[nf][df];
        }
    }
}

// ---------------- fused GIN MLP: u = relu(relu(A@W1+b1)@W2+b2) --------------
// t tile staged in LDS (bf16, uint4-slot XOR swizzle col4 ^= row&15).

__global__ __launch_bounds__(256) void k_gemm_gin(
    const uint4* __restrict__ A,
    const uint4* __restrict__ W1f, const uint4* __restrict__ W2f,
    const float* __restrict__ b1, const float* __restrict__ b2,
    float* __restrict__ outF, float* __restrict__ gsum, float* __restrict__ gsq,
    int N) {
    __shared__ uint4 tile[2048];        // 32 KB t tile
    __shared__ float sred[4][128][2];
    const int tid = threadIdx.x;
    const int lane = tid & 63, wid = tid >> 6;
    const int nbase = blockIdx.x * 128 + wid * 32;
    const int l16 = lane & 15, lg = lane >> 4;

    f4v acc[2][8];
#pragma unroll
    for (int nf = 0; nf < 2; nf++)
#pragma unroll
        for (int df = 0; df < 8; df++)
            acc[nf][df] = (f4v){0.f, 0.f, 0.f, 0.f};

    // ---- stage 1: t = relu(A@W1 + b1) -> LDS (bf16) ----
    {
        const uint4* Whi = W1f;
        const uint4* Wlo = W1f + 2048;
        uint4 bvec[2][4];
#pragma unroll
        for (int nf = 0; nf < 2; nf++) {
            const uint4* row = A + (size_t)(nbase + nf * 16 + l16) * 16;
#pragma unroll
            for (int ks = 0; ks < 4; ks++) bvec[nf][ks] = row[ks * 4 + lg];
        }
        MFMA_STAGE(Whi, Wlo, bvec[0], bvec[1], acc)
    }
#pragma unroll
    for (int df = 0; df < 8; df++) {
        int d0 = df * 16 + lg * 4;
        const float4 bb = *reinterpret_cast<const float4*>(b1 + d0);
#pragma unroll
        for (int nf = 0; nf < 2; nf++) {
            float tx = fmaxf(acc[nf][df][0] + bb.x, 0.f);
            float ty = fmaxf(acc[nf][df][1] + bb.y, 0.f);
            float tz = fmaxf(acc[nf][df][2] + bb.z, 0.f);
            float tw = fmaxf(acc[nf][df][3] + bb.w, 0.f);
            uint2 p;
            p.x = pk2(tx, ty);
            p.y = pk2(tz, tw);
            int row = wid * 32 + nf * 16 + l16;           // local row 0..127
            int col4 = df * 2 + (lg >> 1);                // uint4 slot 0..15
            int slot = row * 16 + (col4 ^ (row & 15));
            *reinterpret_cast<uint2*>(
                reinterpret_cast<char*>(tile) + (size_t)slot * 16 + (lg & 1) * 8) = p;
        }
    }
    __syncthreads();

    // ---- stage 2: u = relu(t@W2 + b2) ----
#pragma unroll
    for (int nf = 0; nf < 2; nf++)
#pragma unroll
        for (int df = 0; df < 8; df++)
            acc[nf][df] = (f4v){0.f, 0.f, 0.f, 0.f};
    {
        const uint4* Whi = W2f;
        const uint4* Wlo = W2f + 2048;
        uint4 bvec[2][4];
#pragma unroll
        for (int nf = 0; nf < 2; nf++) {
            int row = wid * 32 + nf * 16 + l16;
#pragma unroll
            for (int ks = 0; ks < 4; ks++)
                bvec[nf][ks] = tile[row * 16 + ((ks * 4 + lg) ^ (row & 15))];
        }
        MFMA_STAGE(Whi, Wlo, bvec[0], bvec[1], acc)
    }

    const bool v0 = (nbase + l16) < N;
    const bool v1 = (nbase + 16 + l16) < N;
    float4 oo[2][8];
#pragma unroll
    for (int df = 0; df < 8; df++) {
        int d0 = df * 16 + lg * 4;
        const float4 bb = *reinterpret_cast<const float4*>(b2 + d0);
#pragma unroll
        for (int nf = 0; nf < 2; nf++) {
            oo[nf][df].x = fmaxf(acc[nf][df][0] + bb.x, 0.f);
            oo[nf][df].y = fmaxf(acc[nf][df][1] + bb.y, 0.f);
            oo[nf][df].z = fmaxf(acc[nf][df][2] + bb.z, 0.f);
            oo[nf][df].w = fmaxf(acc[nf][df][3] + bb.w, 0.f);
        }
    }

    STATS_EPILOGUE(oo, v0, v1)

#pragma unroll
    for (int nf = 0; nf < 2; nf++) {
        int n = nbase + nf * 16 + l16;
        if (n < N) {
#pragma unroll
            for (int df = 0; df < 8; df++)
                *reinterpret_cast<float4*>(outF + (size_t)n * 384 + df * 16 + lg * 4) = oo[nf][df];
        }
    }
}

// ---------------- fused BN-finalize + normalize (in place) + add-pool ------
// a,c recomputed per thread from raw stats (identical f32 math as old bnfin).

__global__ __launch_bounds__(384) void k_finpool(float* __restrict__ nf,
                                                 const float* __restrict__ gsum,
                                                 const float* __restrict__ gsq,
                                                 const float* __restrict__ gamma,
                                                 const float* __restrict__ beta,
                                                 float invN,
                                                 const int* __restrict__ batch,
                                                 int N, float* __restrict__ pooled) {
    const int d = threadIdx.x;  // 384 = 3 layers x 128 ch, stats laid out [3][128]
    float mu = gsum[d] * invN;
    float var = gsq[d] * invN - mu * mu;
    float rs = rsqrtf(var + BN_EPS);
    const float a = gamma[d] * rs;
    const float c = beta[d] - mu * a;

    const int n0 = blockIdx.x * 64;
    const int n1 = min(n0 + 64, N);
    float s = 0.f;
    int curg = batch[n0];
    for (int n = n0; n < n1; n++) {
        int g = batch[n];
        if (g != curg) {
            unsafeAtomicAdd(&pooled[(size_t)curg * 384 + d], s);
            s = 0.f;
            curg = g;
        }
        float v = nf[(size_t)n * 384 + d];
        float h = fmaf(v, a, c);
        nf[(size_t)n * 384 + d] = h;
        s += h;
    }
    unsafeAtomicAdd(&pooled[(size_t)curg * 384 + d], s);
}

// ---------------- launch ----------------

extern "C" void kernel_launch(void* const* d_in, const int* in_sizes, int n_in,
                              void* d_out, int out_size, void* d_ws, size_t ws_size,
                              hipStream_t stream) {
    const float* x   = (const float*)d_in[0];
    const int*   ei  = (const int*)d_in[1];
    const int*   bat = (const int*)d_in[2];
    const float* sWl = (const float*)d_in[3];
    const float* sbl = (const float*)d_in[4];
    const float* sWr = (const float*)d_in[5];
    const float* gW1 = (const float*)d_in[6];
    const float* gb1 = (const float*)d_in[7];
    const float* gW2 = (const float*)d_in[8];
    const float* gb2 = (const float*)d_in[9];
    const float* bng = (const float*)d_in[10];
    const float* bnb = (const float*)d_in[11];

    const int N = in_sizes[0] / 128;
    const int E = in_sizes[1] / 2;
    const int G = out_size / 384 - N;
    const int* srcp = ei;
    const int* dstp = ei + E;

    char* w = (char*)d_ws;
    auto alloc = [&](size_t bytes) -> void* {
        void* p = (void*)w;
        w += (bytes + 255) & ~(size_t)255;
        return p;
    };
    const size_t Npad = (size_t)(N + 128);
    int*   rp    = (int*)alloc(((size_t)N + 1) * 4);
    int*   csr   = (int*)alloc((size_t)E * 4);
    // contiguous zero region: bcnt (2048B) + gsum[3][128] + gsq[3][128]
    char*  zreg  = (char*)alloc(2048 + 2 * 3 * 512);
    int*   bcnt  = (int*)zreg;
    float* gsum  = (float*)(zreg + 2048);
    float* gsq   = gsum + 3 * 128;
    // 6 weights x (hi+lo) x 16384 bf16: sWl, sWr, W1[0], W2[0], W1[1], W2[1]
    unsigned short* Wp = (unsigned short*)alloc((size_t)6 * 2 * 16384 * 2);
    unsigned short* ab = (unsigned short*)alloc(Npad * 256);  // aggregates / ebuf
    unsigned short* tb = (unsigned short*)alloc(Npad * 256);  // x / h tables

    float* pooled = (float*)d_out;                 // [G][384]
    float* nf     = pooled + (size_t)G * 384;      // [N][384]

    const float invN = 1.0f / (float)N;

    // bucket geometry (bucket = dst >> 8)
    const int NB  = (N + 255) / 256;
    int CAP = ((2 * (E / (NB > 0 ? NB : 1)) + 511) / 512) * 512;
    const long long maxcap = (long long)(Npad * 256) / ((long long)NB * 8);
    if ((long long)CAP > maxcap) CAP = (int)(maxcap & ~511LL);
    unsigned long long* ebuf = (unsigned long long*)ab;  // aliases ab

    const int egrid = (E + EPB - 1) / EPB;
    const int agrid = (N + 3) / 4;
    const int ggrid = (N + 127) / 128;
    const int vgrid = (N * 16 + 255) / 256;
    const int fgrid = (N + 63) / 64;

    // ---- zero counters/stats + pooled ----
    hipMemsetAsync(zreg, 0, 2048 + 2 * 3 * 512, stream);
    hipMemsetAsync(pooled, 0, (size_t)G * 384 * 4, stream);

    // ---- CSR build (binned; prefix scan inlined in pass B) ----
    k_binA<<<egrid, 256, 0, stream>>>(srcp, dstp, E, NB, CAP, bcnt, ebuf);
    k_binB<<<NB, 256, 0, stream>>>(ebuf, CAP, bcnt, N, E, rp, csr);

    // ---- prep: x -> bf16 (tb), all weight packs in one dispatch ----
    k_cvt_bf16<<<vgrid, 256, 0, stream>>>(x, (uint4*)tb, N * 16);
    k_pack_all<<<6 * 64, 256, 0, stream>>>(sWl, sWr, gW1, gW2, Wp);

    // ---- Layer 0: SAGE ----
    k_aggr<false, true><<<agrid, 256, 0, stream>>>(rp, csr, (const uint4*)tb, (uint4*)ab, N);
    k_gemm_sage<<<ggrid, 256, 0, stream>>>(
        (const uint4*)ab, (const uint4*)tb, (const uint4*)Wp, sbl, nf, gsum, gsq, N);
    // h0 table (bf16, rounded AFTER normalization; a,c computed in-kernel)
    k_cvt_h<<<vgrid, 256, 0, stream>>>(nf, gsum, gsq, bng, bnb, invN, (uint4*)tb, N);

    // ---- Layers 1,2: GIN ----
    for (int l = 1; l < 3; l++) {
        const uint4* W1p = (const uint4*)(Wp + (size_t)(2 * l) * 32768);      // slots 2,4
        const uint4* W2p = (const uint4*)(Wp + (size_t)(2 * l + 1) * 32768);  // slots 3,5
        const float* b1 = gb1 + (size_t)(l - 1) * 128;
        const float* b2 = gb2 + (size_t)(l - 1) * 128;
        float* nfl = nf + (size_t)l * 128;

        // ab = h + sum_nb h  (gather from tb)
        k_aggr<true, false><<<agrid, 256, 0, stream>>>(rp, csr, (const uint4*)tb, (uint4*)ab, N);
        // u = relu(relu(ab@W1+b1)@W2+b2) -> nf_l (f32) + stats (layer slot l)
        k_gemm_gin<<<ggrid, 256, 0, stream>>>(
            (const uint4*)ab, W1p, W2p, b1, b2, nfl, gsum + l * 128, gsq + l * 128, N);
        // h_l table for next gather (only layer 1 needs it)
        if (l < 2)
            k_cvt_h<<<vgrid, 256, 0, stream>>>(nfl, gsum + l * 128, gsq + l * 128,
                                               bng + l * 128, bnb + l * 128, invN,
                                               (uint4*)tb, N);
    }

    // ---- fused BN-finalize + normalize + pool ----
    k_finpool<<<fgrid, 384, 0, stream>>>(nf, gsum, gsq, bng, bnb, invN, bat, N, pooled);
}